// Round 1
// baseline (7529.235 us; speedup 1.0000x reference)
//
#include <hip/hip_runtime.h>
#include <stdint.h>

typedef unsigned short u16;
typedef unsigned int   u32;

// ---------- bf16 helpers (manual, RNE) ----------
__device__ __forceinline__ float blo(u32 u){ u32 i = u << 16; float f; __builtin_memcpy(&f,&i,4); return f; }
__device__ __forceinline__ float bhi(u32 u){ u32 i = u & 0xFFFF0000u; float f; __builtin_memcpy(&f,&i,4); return f; }
__device__ __forceinline__ float b2f(u16 u){ u32 i = ((u32)u) << 16; float f; __builtin_memcpy(&f,&i,4); return f; }
__device__ __forceinline__ u16 f2b(float f){ u32 i; __builtin_memcpy(&i,&f,4); i += 0x7FFFu + ((i>>16)&1u); return (u16)(i>>16); }

// ---------- weight prep ----------
// conv: w (Cout,Cin,3,3) f32 -> wb[k*Cout+co], k=(kh*3+kw)*Cin+ci, value=sign
__global__ void k_prep_conv_w(const float* __restrict__ w, u16* __restrict__ wb, int Cout, int Cin){
  int total = Cout*Cin*9;
  for(int i = blockIdx.x*256 + threadIdx.x; i < total; i += gridDim.x*256){
    int co = i % Cout; int k = i / Cout;
    int tap = k / Cin; int ci = k - tap*Cin;
    float v = w[(size_t)(co*Cin + ci)*9 + tap];
    wb[i] = (v >= 0.f) ? (u16)0x3F80 : (u16)0xBF80;
  }
}
// fc: w (Nf,K) f32 -> wb[k*Nf+n]; permute=1 remaps our NHWC-flat k=(p*512+c) to ref k=(c*16+p)
__global__ void k_prep_fc_w(const float* __restrict__ w, u16* __restrict__ wb, int Nf, int K, int permute){
  int total = Nf*K;
  for(int i = blockIdx.x*256 + threadIdx.x; i < total; i += gridDim.x*256){
    int n = i % Nf; int k = i / Nf;
    int kr = k;
    if(permute){ int c = k & 511; int p = k >> 9; kr = c*16 + p; }
    float v = w[(size_t)n*K + kr];
    wb[i] = (v >= 0.f) ? (u16)0x3F80 : (u16)0xBF80;
  }
}

// x (256,3,32,32) f32 NCHW -> p (256,34,34,3) bf16 NHWC edge-padded
__global__ void k_pad_input(const float* __restrict__ x, u16* __restrict__ p){
  int total = 256*34*34*3;
  for(int i = blockIdx.x*256 + threadIdx.x; i < total; i += gridDim.x*256){
    int c = i % 3; int t = i / 3; int wp = t % 34; t /= 34; int hp = t % 34; int n = t / 34;
    int h = hp-1; h = h<0?0:(h>31?31:h);
    int w = wp-1; w = w<0?0:(w>31?31:w);
    p[i] = f2b(x[((size_t)(n*3+c)*32 + h)*32 + w]);
  }
}

// ---------- conv: implicit GEMM, 64 pixels x 64 couts per block, fp32 acc ----------
// xp: (N,H+2,W+2,Cin) bf16 padded; wb: (9*Cin, Cout); y: (N,H,W,Cout) = conv+bias
__global__ __launch_bounds__(256) void k_conv(
    const u16* __restrict__ xp, const u16* __restrict__ wb, const float* __restrict__ bias,
    u16* __restrict__ y, int H, int W, int Cin, int Cout, int R)
{
  extern __shared__ u16 lds[];
  const int Wp = W + 2;
  const int CS = (Cin < 256) ? Cin : 256;     // channel split keeps LDS <= 64KB
  const int S  = CS + 2;                      // padded pixel stride (bank-conflict fix)
  u16* lx = lds;
  u16* lw = lds + (R+2)*Wp*S;
  const bool smallC = (Cin < 64);
  const int tid = threadIdx.x;
  const int hblocks = H / R;
  const int n  = blockIdx.x / hblocks;
  const int rb = blockIdx.x - n*hblocks;
  const int h0 = rb * R;
  const int cob = blockIdx.y * 64;
  const int pg = tid & 15, cgi = tid >> 4;
  const int wLog = (W==32)?5:((W==16)?4:3);

  int offp[4], hh[4], wwv[4];
  #pragma unroll
  for(int p=0;p<4;p++){
    int lp = pg*4 + p; int rl = lp >> wLog; int w_ = lp & (W-1);
    offp[p] = (rl*Wp + w_)*S; hh[p] = h0 + rl; wwv[p] = w_;
  }
  float acc[4][4] = {};

  const u16* gx = xp + ((size_t)n*(H+2) + h0) * (size_t)(Wp*Cin);
  const int halves = Cin / CS;                // 1 or 2
  const int slabh = (R+2)*Wp*CS;

  for(int hv=0; hv<halves; hv++){
    __syncthreads();
    if(!smallC){
      const int csLog = (CS==256)?8:7;
      const int total8 = slabh >> 3;
      for(int i8=tid; i8<total8; i8+=256){
        int e = i8 << 3; int pix = e >> csLog; int ci = e & (CS-1);
        uint4 v = *(const uint4*)(gx + (size_t)pix*Cin + hv*CS + ci);
        u16* d = lx + pix*S + ci;
        ((u32*)d)[0]=v.x; ((u32*)d)[1]=v.y; ((u32*)d)[2]=v.z; ((u32*)d)[3]=v.w;
      }
    } else {
      for(int e=tid; e<slabh; e+=256){ int pix = e/Cin, ci = e - pix*Cin; lx[pix*S+ci] = gx[(size_t)pix*Cin + ci]; }
    }
    for(int tap=0; tap<9; tap++){
      const int dh = tap/3, dw = tap - dh*3;
      const int toff = (dh*Wp + dw)*S;
      for(int ci0=0; ci0<CS; ci0+=64){
        const int CK = (CS - ci0 < 64) ? (CS - ci0) : 64;
        __syncthreads();
        for(int i=tid; i<CK*8; i+=256){
          int kk = i>>3, seg = i&7;
          *(uint4*)(lw + kk*64 + seg*8) =
            *(const uint4*)(wb + (size_t)(tap*Cin + hv*CS + ci0 + kk)*Cout + cob + seg*8);
        }
        __syncthreads();
        const int abase = toff + ci0;
        if(!smallC){
          for(int kk=0; kk<CK; kk+=2){
            uint2 bA = *(const uint2*)(lw + kk*64 + cgi*4);
            uint2 bB = *(const uint2*)(lw + (kk+1)*64 + cgi*4);
            float bA0=blo(bA.x),bA1=bhi(bA.x),bA2=blo(bA.y),bA3=bhi(bA.y);
            float bB0=blo(bB.x),bB1=bhi(bB.x),bB2=blo(bB.y),bB3=bhi(bB.y);
            #pragma unroll
            for(int p=0;p<4;p++){
              u32 av = *(const u32*)(lx + offp[p] + abase + kk);
              float a0 = blo(av), a1 = bhi(av);
              acc[p][0] = fmaf(a0,bA0, fmaf(a1,bB0, acc[p][0]));
              acc[p][1] = fmaf(a0,bA1, fmaf(a1,bB1, acc[p][1]));
              acc[p][2] = fmaf(a0,bA2, fmaf(a1,bB2, acc[p][2]));
              acc[p][3] = fmaf(a0,bA3, fmaf(a1,bB3, acc[p][3]));
            }
          }
        } else {
          for(int kk=0; kk<CK; kk++){
            uint2 bv = *(const uint2*)(lw + kk*64 + cgi*4);
            float b0=blo(bv.x),b1=bhi(bv.x),b2=blo(bv.y),b3=bhi(bv.y);
            #pragma unroll
            for(int p=0;p<4;p++){
              float a = b2f(lx[offp[p] + abase + kk]);
              acc[p][0] += a*b0; acc[p][1] += a*b1; acc[p][2] += a*b2; acc[p][3] += a*b3;
            }
          }
        }
      }
    }
  }
  float bs0=bias[cob+cgi*4+0], bs1=bias[cob+cgi*4+1], bs2=bias[cob+cgi*4+2], bs3=bias[cob+cgi*4+3];
  #pragma unroll
  for(int p=0;p<4;p++){
    size_t o = (((size_t)n*H + hh[p])*W + wwv[p])*(size_t)Cout + cob + cgi*4;
    u32 w0 = (u32)f2b(acc[p][0]+bs0) | ((u32)f2b(acc[p][1]+bs1) << 16);
    u32 w1 = (u32)f2b(acc[p][2]+bs2) | ((u32)f2b(acc[p][3]+bs3) << 16);
    ((u32*)(y + o))[0] = w0; ((u32*)(y + o))[1] = w1;
  }
}

// ---------- 2x2 maxpool (NHWC) ----------
__global__ void k_pool(const u16* __restrict__ in, u16* __restrict__ out, int HO, int WO, int C){
  int cpg = C >> 3;
  int total = 256*HO*WO*cpg;
  for(int i = blockIdx.x*256 + threadIdx.x; i < total; i += gridDim.x*256){
    int c8 = i % cpg; int t = i / cpg;
    int wo = t % WO; t /= WO; int ho = t % HO; int n = t / HO;
    const int Wi = 2*WO;
    const u16* p = in + (((size_t)(n*2*HO + 2*ho))*Wi + 2*wo)*C + c8*8;
    uint4 v00 = *(const uint4*)p;
    uint4 v01 = *(const uint4*)(p + C);
    uint4 v10 = *(const uint4*)(p + (size_t)Wi*C);
    uint4 v11 = *(const uint4*)(p + (size_t)Wi*C + C);
    u32 a[4]={v00.x,v00.y,v00.z,v00.w}, b[4]={v01.x,v01.y,v01.z,v01.w};
    u32 c[4]={v10.x,v10.y,v10.z,v10.w}, d[4]={v11.x,v11.y,v11.z,v11.w};
    u32 o[4];
    #pragma unroll
    for(int j=0;j<4;j++){
      float l = fmaxf(fmaxf(blo(a[j]),blo(b[j])), fmaxf(blo(c[j]),blo(d[j])));
      float h = fmaxf(fmaxf(bhi(a[j]),bhi(b[j])), fmaxf(bhi(c[j]),bhi(d[j])));
      o[j] = (u32)f2b(l) | ((u32)f2b(h)<<16);
    }
    uint4 ov; ov.x=o[0]; ov.y=o[1]; ov.z=o[2]; ov.w=o[3];
    *(uint4*)(out + ((size_t)(n*HO + ho)*WO + wo)*C + c8*8) = ov;
  }
}

// ---------- per-channel sum/sumsq partials ----------
__global__ __launch_bounds__(256) void k_stats(const u16* __restrict__ in, float* __restrict__ part,
                                               int total, int C, int CH){
  extern __shared__ float ls[];
  const int tid = threadIdx.x; const int b = blockIdx.x;
  const int cpg = C >> 3;
  const bool pow2p = ((C & 7)==0) && (cpg>0) && ((256 % cpg)==0);
  if(pow2p){
    int total8 = total >> 3;
    int per = ((total8 + CH - 1)/CH + 255) & ~255;
    int s = b*per; int e = s+per; if(e>total8) e=total8;
    float sm[8]={0,0,0,0,0,0,0,0}, sq[8]={0,0,0,0,0,0,0,0};
    for(int i=s+tid; i<e; i+=256){
      uint4 v = *(const uint4*)(in + ((size_t)i<<3));
      u32 a[4]={v.x,v.y,v.z,v.w};
      #pragma unroll
      for(int j=0;j<4;j++){ float lo=blo(a[j]), hi=bhi(a[j]);
        sm[2*j]+=lo; sq[2*j]+=lo*lo; sm[2*j+1]+=hi; sq[2*j+1]+=hi*hi; }
    }
    #pragma unroll
    for(int j=0;j<8;j++){ ls[tid*16+j]=sm[j]; ls[tid*16+8+j]=sq[j]; }
    __syncthreads();
    int G = 256/cpg;
    for(int c=tid;c<C;c+=256){
      int c8=c>>3, j=c&7; float ssum=0.f, ssq=0.f;
      for(int g=0; g<G; g++){ int t = g*cpg + c8; ssum += ls[t*16+j]; ssq += ls[t*16+8+j]; }
      part[(size_t)b*2*C + c] = ssum; part[(size_t)b*2*C + C + c] = ssq;
    }
  } else if((C & 7)==0){
    for(int i=tid;i<2*C;i+=256) ls[i]=0.f;
    __syncthreads();
    int total8 = total >> 3;
    int per = (total8 + CH - 1)/CH;
    int s = b*per; int e = s+per; if(e>total8) e=total8;
    for(int i=s+tid;i<e;i+=256){
      uint4 v = *(const uint4*)(in + ((size_t)i<<3));
      int c0 = (i % cpg)*8;
      u32 a[4]={v.x,v.y,v.z,v.w};
      #pragma unroll
      for(int j=0;j<4;j++){
        float lo=blo(a[j]), hi=bhi(a[j]);
        atomicAdd(&ls[c0+2*j], lo);   atomicAdd(&ls[C+c0+2*j], lo*lo);
        atomicAdd(&ls[c0+2*j+1], hi); atomicAdd(&ls[C+c0+2*j+1], hi*hi);
      }
    }
    __syncthreads();
    for(int c=tid;c<2*C;c+=256) part[(size_t)b*2*C + c] = ls[c];
  } else {
    for(int i=tid;i<2*C;i+=256) ls[i]=0.f;
    __syncthreads();
    int per = (total + CH - 1)/CH;
    int s = b*per; int e = s+per; if(e>total) e=total;
    for(int i=s+tid;i<e;i+=256){
      float v = b2f(in[i]); int c = i % C;
      atomicAdd(&ls[c], v); atomicAdd(&ls[C+c], v*v);
    }
    __syncthreads();
    for(int c=tid;c<2*C;c+=256) part[(size_t)b*2*C + c] = ls[c];
  }
}

// reduce partials -> per-channel affine A=g*rsqrt(var+eps), B=bt-mean*A
__global__ void k_bn_prep(const float* __restrict__ part, const float* __restrict__ g,
                          const float* __restrict__ bt, float* __restrict__ AB,
                          int C, int CH, float invCnt){
  int c = blockIdx.x*256 + threadIdx.x; if(c>=C) return;
  float s=0.f, q=0.f;
  for(int b=0;b<CH;b++){ s += part[(size_t)b*2*C + c]; q += part[(size_t)b*2*C + C + c]; }
  float m = s*invCnt; float v = q*invCnt - m*m;
  float rs = rsqrtf(v + 1e-5f);
  float A = g[c]*rs;
  AB[c] = A; AB[C+c] = bt[c] - m*A;
}

// normalize + (hardtanh) + write (padded-with-edge-replication, or flat)
__global__ void k_bn_act(const u16* __restrict__ in, const float* __restrict__ AB,
                         u16* __restrict__ out, int C, int rows, int HO, int WO,
                         int padMode, int clampF){
  int cpg = C >> 3;
  int total = rows * cpg;
  for(int i = blockIdx.x*256 + threadIdx.x; i < total; i += gridDim.x*256){
    int c8 = i % cpg; int row = i / cpg; int c0 = c8*8;
    uint4 v = *(const uint4*)(in + (size_t)i*8);
    float4 A0 = *(const float4*)(AB + c0);
    float4 A1 = *(const float4*)(AB + c0 + 4);
    float4 B0 = *(const float4*)(AB + C + c0);
    float4 B1 = *(const float4*)(AB + C + c0 + 4);
    u32 a[4]={v.x,v.y,v.z,v.w};
    float f[8];
    f[0]=blo(a[0])*A0.x+B0.x; f[1]=bhi(a[0])*A0.y+B0.y;
    f[2]=blo(a[1])*A0.z+B0.z; f[3]=bhi(a[1])*A0.w+B0.w;
    f[4]=blo(a[2])*A1.x+B1.x; f[5]=bhi(a[2])*A1.y+B1.y;
    f[6]=blo(a[3])*A1.z+B1.z; f[7]=bhi(a[3])*A1.w+B1.w;
    if(clampF){
      #pragma unroll
      for(int j=0;j<8;j++) f[j] = fminf(fmaxf(f[j], -1.f), 1.f);
    }
    uint4 o;
    o.x = (u32)f2b(f[0]) | ((u32)f2b(f[1])<<16);
    o.y = (u32)f2b(f[2]) | ((u32)f2b(f[3])<<16);
    o.z = (u32)f2b(f[4]) | ((u32)f2b(f[5])<<16);
    o.w = (u32)f2b(f[6]) | ((u32)f2b(f[7])<<16);
    if(!padMode){
      *(uint4*)(out + (size_t)i*8) = o;
    } else {
      int w = row % WO; int t = row / WO; int h = t % HO; int n = t / HO;
      int Wp2 = WO + 2;
      size_t base = (size_t)n*(HO+2)*Wp2;
      u16* ob = out;
      #define WRP(hp,wp) *(uint4*)(ob + ((base + (size_t)(hp)*Wp2 + (wp))*C) + c0) = o
      WRP(h+1, w+1);
      if(h==0)            WRP(0,    w+1);
      if(h==HO-1)         WRP(HO+1, w+1);
      if(w==0)            WRP(h+1,  0);
      if(w==WO-1)         WRP(h+1,  WO+1);
      if(h==0    && w==0)    WRP(0,    0);
      if(h==0    && w==WO-1) WRP(0,    WO+1);
      if(h==HO-1 && w==0)    WRP(HO+1, 0);
      if(h==HO-1 && w==WO-1) WRP(HO+1, WO+1);
      #undef WRP
    }
  }
}

// ---------- FC tiled GEMM (split-K, fp32 partials) ----------
__global__ __launch_bounds__(256) void k_gemm(
    const u16* __restrict__ A, const u16* __restrict__ B, float* __restrict__ P,
    int M, int Nf, int K, int KC, int ncp)
{
  __shared__ u16 la[64*66];
  __shared__ u16 lb[64*64];
  const int tid = threadIdx.x;
  const int pg = tid & 15, cgi = tid >> 4;
  const int mb = blockIdx.x * 64, nb = blockIdx.y * 64, kz = blockIdx.z;
  float acc[4][4] = {};
  for(int kc = kz*KC; kc < kz*KC + KC; kc += 64){
    __syncthreads();
    {
      int r = tid >> 2, seg = tid & 3;
      const u16* g = A + (size_t)(mb + r)*K + kc + seg*16;
      uint4 v0 = *(const uint4*)g;
      uint4 v1 = *(const uint4*)(g + 8);
      u16* d = la + r*66 + seg*16;
      ((u32*)d)[0]=v0.x; ((u32*)d)[1]=v0.y; ((u32*)d)[2]=v0.z; ((u32*)d)[3]=v0.w;
      ((u32*)d)[4]=v1.x; ((u32*)d)[5]=v1.y; ((u32*)d)[6]=v1.z; ((u32*)d)[7]=v1.w;
    }
    for(int i=tid; i<512; i+=256){
      int kk = i>>3, seg = i&7;
      int gn = nb + seg*8;
      if((Nf & 63) == 0){
        *(uint4*)(lb + kk*64 + seg*8) = *(const uint4*)(B + (size_t)(kc+kk)*Nf + gn);
      } else {
        u16 tmp[8];
        #pragma unroll
        for(int j=0;j<8;j++) tmp[j] = (gn + j < Nf) ? B[(size_t)(kc+kk)*Nf + gn + j] : (u16)0;
        *(uint4*)(lb + kk*64 + seg*8) = *(uint4*)tmp;
      }
    }
    __syncthreads();
    for(int kk=0; kk<64; kk+=2){
      uint2 bA = *(const uint2*)(lb + kk*64 + cgi*4);
      uint2 bB = *(const uint2*)(lb + (kk+1)*64 + cgi*4);
      float bA0=blo(bA.x),bA1=bhi(bA.x),bA2=blo(bA.y),bA3=bhi(bA.y);
      float bB0=blo(bB.x),bB1=bhi(bB.x),bB2=blo(bB.y),bB3=bhi(bB.y);
      #pragma unroll
      for(int p=0;p<4;p++){
        u32 av = *(const u32*)(la + (pg*4+p)*66 + kk);
        float a0 = blo(av), a1 = bhi(av);
        acc[p][0] = fmaf(a0,bA0, fmaf(a1,bB0, acc[p][0]));
        acc[p][1] = fmaf(a0,bA1, fmaf(a1,bB1, acc[p][1]));
        acc[p][2] = fmaf(a0,bA2, fmaf(a1,bB2, acc[p][2]));
        acc[p][3] = fmaf(a0,bA3, fmaf(a1,bB3, acc[p][3]));
      }
    }
  }
  #pragma unroll
  for(int p=0;p<4;p++){
    int m = mb + pg*4 + p;
    float* d = P + ((size_t)kz*M + m)*ncp + nb + cgi*4;
    d[0]=acc[p][0]; d[1]=acc[p][1]; d[2]=acc[p][2]; d[3]=acc[p][3];
  }
}

__global__ void k_fc_finish(const float* __restrict__ P, const float* __restrict__ bias,
                            u16* __restrict__ y, int M, int Nf, int ncp, int CH){
  int total = M*Nf;
  for(int i = blockIdx.x*256 + threadIdx.x; i < total; i += gridDim.x*256){
    int nf = i % Nf; int m = i / Nf;
    float s = bias[nf];
    for(int z=0; z<CH; z++) s += P[((size_t)z*M + m)*ncp + nf];
    y[i] = f2b(s);
  }
}

__global__ void k_final(const u16* __restrict__ y, const float* __restrict__ AB,
                        float* __restrict__ out, int C, int total){
  for(int i = blockIdx.x*256 + threadIdx.x; i < total; i += gridDim.x*256){
    int c = i % C;
    out[i] = b2f(y[i])*AB[c] + AB[C+c];
  }
}

// ================= host =================
extern "C" void kernel_launch(void* const* d_in, const int* in_sizes, int n_in,
                              void* d_out, int out_size, void* d_ws, size_t ws_size,
                              hipStream_t stream) {
  (void)in_sizes; (void)n_in; (void)out_size; (void)ws_size;
  const float* x = (const float*)d_in[0];
  const float *cw[6], *cb[6], *cgam[6], *cbt[6];
  for(int i=0;i<6;i++){
    cw[i]  =(const float*)d_in[1+4*i];
    cb[i]  =(const float*)d_in[2+4*i];
    cgam[i]=(const float*)d_in[3+4*i];
    cbt[i] =(const float*)d_in[4+4*i];
  }
  const float *fw[3], *fbias[3], *fg[3], *fbt[3];
  for(int i=0;i<3;i++){
    fw[i]   =(const float*)d_in[25+4*i];
    fbias[i]=(const float*)d_in[26+4*i];
    fg[i]   =(const float*)d_in[27+4*i];
    fbt[i]  =(const float*)d_in[28+4*i];
  }

  char* ws = (char*)d_ws;
  size_t off = 0;
  auto alloc = [&](size_t bytes){ size_t o = off; off = (off + bytes + 255) & ~(size_t)255; return o; };
  const size_t oP = alloc((size_t)37879808*2);   // padded acts, max 256*34*34*128
  const size_t oY = alloc((size_t)33554432*2);   // raw conv out, max 256*32*32*128
  const size_t oQ = alloc((size_t)8388608*2);    // pooled, max 256*16*16*128
  const int CinA[6]  = {3,128,128,256,256,512};
  const int CoutA[6] = {128,128,256,256,512,512};
  size_t oWc[6];
  for(int l=0;l<6;l++) oWc[l] = alloc((size_t)CoutA[l]*CinA[l]*9*2);
  const size_t oW1 = alloc((size_t)8192*1536*2);
  const size_t oW2 = alloc((size_t)1536*1536*2);
  const size_t oW3 = alloc((size_t)1536*10*2);
  const size_t oSP = alloc((size_t)256*2*1536*4); // stats partials
  const size_t oAB = alloc((size_t)2*1536*4);

  u16*   Pbuf = (u16*)(ws + oP);
  u16*   Ybuf = (u16*)(ws + oY);
  u16*   Qbuf = (u16*)(ws + oQ);
  float* SP   = (float*)(ws + oSP);
  float* AB   = (float*)(ws + oAB);
  // FC buffers carved from the (dead-by-then) conv-Y region
  u16*   F0 = (u16*)(ws + oY + (size_t)17*1024*1024);  // 256x8192 bf16
  u16*   FA = (u16*)(ws + oY + (size_t)22*1024*1024);  // 256x1536 bf16
  u16*   FB = (u16*)(ws + oY + (size_t)23*1024*1024);  // 256x1536 bf16
  float* Pg = (float*)(ws + oY + (size_t)24*1024*1024);// split-K partials (<=12.6MB)

  // weight prep
  for(int l=0;l<6;l++)
    k_prep_conv_w<<<1024,256,0,stream>>>(cw[l], (u16*)(ws+oWc[l]), CoutA[l], CinA[l]);
  k_prep_fc_w<<<2048,256,0,stream>>>(fw[0], (u16*)(ws+oW1), 1536, 8192, 1);
  k_prep_fc_w<<<1024,256,0,stream>>>(fw[1], (u16*)(ws+oW2), 1536, 1536, 0);
  k_prep_fc_w<<<64,256,0,stream>>>  (fw[2], (u16*)(ws+oW3), 10,   1536, 0);
  k_pad_input<<<2048,256,0,stream>>>(x, Pbuf);

  // conv blocks
  const int Harr[6] = {32,32,16,16,8,8};
  const int pool[6] = {0,1,0,1,0,1};
  for(int l=0;l<6;l++){
    int H=Harr[l], W=H, Cin=CinA[l], Cout=CoutA[l];
    int R = (W==32)?2:((W==16)?4:8);
    int CS = (Cin<256)?Cin:256; int S = CS+2;
    size_t shmem = ((size_t)(R+2)*(W+2)*S + 4096)*2;
    dim3 g(256*(H/R), Cout/64);
    k_conv<<<g,256,shmem,stream>>>(Pbuf, (u16*)(ws+oWc[l]), cb[l], Ybuf, H, W, Cin, Cout, R);
    const u16* sIn; int rowsS; int HO;
    if(pool[l]){
      HO=H/2;
      k_pool<<<2048,256,0,stream>>>(Ybuf, Qbuf, HO, HO, Cout);
      sIn=Qbuf; rowsS=256*HO*HO;
    } else { HO=H; sIn=Ybuf; rowsS=256*H*H; }
    int total = rowsS*Cout;
    int CH = 256;
    k_stats<<<CH,256,16384,stream>>>(sIn, SP, total, Cout, CH);
    k_bn_prep<<<(Cout+255)/256,256,0,stream>>>(SP, cgam[l], cbt[l], AB, Cout, CH, 1.0f/(float)rowsS);
    if(l<5) k_bn_act<<<2048,256,0,stream>>>(sIn, AB, Pbuf, Cout, rowsS, HO, HO, 1, 1);
    else    k_bn_act<<<2048,256,0,stream>>>(sIn, AB, F0,   Cout, rowsS, HO, HO, 0, 1);
  }

  // FC1: 256x8192 @ 8192x1536
  k_gemm<<<dim3(4,24,8),256,0,stream>>>(F0, (u16*)(ws+oW1), Pg, 256,1536,8192,1024,1536);
  k_fc_finish<<<768,256,0,stream>>>(Pg, fbias[0], FA, 256,1536,1536,8);
  k_stats<<<16,256,12288,stream>>>(FA, SP, 256*1536, 1536, 16);
  k_bn_prep<<<6,256,0,stream>>>(SP, fg[0], fbt[0], AB, 1536, 16, 1.0f/256.0f);
  k_bn_act<<<256,256,0,stream>>>(FA, AB, FA, 1536, 256, 0,0, 0, 1);
  // FC2: 256x1536 @ 1536x1536
  k_gemm<<<dim3(4,24,4),256,0,stream>>>(FA, (u16*)(ws+oW2), Pg, 256,1536,1536,384,1536);
  k_fc_finish<<<768,256,0,stream>>>(Pg, fbias[1], FB, 256,1536,1536,4);
  k_stats<<<16,256,12288,stream>>>(FB, SP, 256*1536, 1536, 16);
  k_bn_prep<<<6,256,0,stream>>>(SP, fg[1], fbt[1], AB, 1536, 16, 1.0f/256.0f);
  k_bn_act<<<256,256,0,stream>>>(FB, AB, FB, 1536, 256, 0,0, 0, 1);
  // FC3: 256x1536 @ 1536x10 -> BN (no clamp) -> f32 out
  k_gemm<<<dim3(4,1,4),256,0,stream>>>(FB, (u16*)(ws+oW3), Pg, 256,10,1536,384,64);
  k_fc_finish<<<16,256,0,stream>>>(Pg, fbias[2], FA, 256,10,64,4);
  k_stats<<<4,256,256,stream>>>(FA, SP, 2560, 10, 4);
  k_bn_prep<<<1,256,0,stream>>>(SP, fg[2], fbt[2], AB, 10, 4, 1.0f/256.0f);
  k_final<<<10,256,0,stream>>>(FA, AB, (float*)d_out, 10, 2560);
}

// Round 3
// 2011.245 us; speedup vs baseline: 3.7436x; 3.7436x over previous
//
#include <hip/hip_runtime.h>
#include <stdint.h>

typedef unsigned short u16;
typedef unsigned int   u32;
typedef __attribute__((ext_vector_type(8))) short bf16x8;
typedef __attribute__((ext_vector_type(4))) float f32x4;

__device__ __forceinline__ float b2f(u16 u){ u32 i = ((u32)u) << 16; float f; __builtin_memcpy(&f,&i,4); return f; }
__device__ __forceinline__ u16 f2b(float f){ u32 i; __builtin_memcpy(&i,&f,4); i += 0x7FFFu + ((i>>16)&1u); return (u16)(i>>16); }

// ---------- weight prep: MFMA B-fragment layout ----------
__global__ void k_prep_wfrag_conv(const float* __restrict__ w, u16* __restrict__ wf,
                                  int Cout, int Cin, int KT){
  int NCT = Cout >> 4;
  int total = KT*NCT*512;
  int Kmax = 9*Cin;
  for(int i = blockIdx.x*256 + threadIdx.x; i < total; i += gridDim.x*256){
    int i8 = i & 7; int lane = (i>>3)&63; int t = i>>9;
    int ct = t % NCT; int kt = t / NCT;
    int k = kt*32 + ((lane>>4)<<3) + i8;
    int co = (ct<<4) + (lane&15);
    u16 v = 0;
    if(k < Kmax){
      int tap = k / Cin; int ci = k - tap*Cin;
      v = (w[(size_t)(co*Cin+ci)*9 + tap] >= 0.f) ? (u16)0x3F80 : (u16)0xBF80;
    }
    wf[i] = v;
  }
}
__global__ void k_prep_wfrag_fc(const float* __restrict__ w, u16* __restrict__ wf,
                                int Nf, int K, int NCTp, int permute){
  int total = (K>>5)*NCTp*512;
  for(int i = blockIdx.x*256 + threadIdx.x; i < total; i += gridDim.x*256){
    int i8 = i & 7; int lane = (i>>3)&63; int t = i>>9;
    int ct = t % NCTp; int kt = t / NCTp;
    int k = kt*32 + ((lane>>4)<<3) + i8;
    int n = (ct<<4) + (lane&15);
    u16 v = 0;
    if(n < Nf){
      int kr = permute ? ((k & 511)*16 + (k >> 9)) : k;
      v = (w[(size_t)n*K + kr] >= 0.f) ? (u16)0x3F80 : (u16)0xBF80;
    }
    wf[i] = v;
  }
}

// x (256,3,32,32) f32 NCHW -> (256,34,34,3) bf16 NHWC edge-padded
__global__ void k_pad_input(const float* __restrict__ x, u16* __restrict__ p){
  int total = 256*34*34*3;
  for(int i = blockIdx.x*256 + threadIdx.x; i < total; i += gridDim.x*256){
    int c = i % 3; int t = i / 3; int wp = t % 34; t /= 34; int hp = t % 34; int n = t / 34;
    int h = hp-1; h = h<0?0:(h>31?31:h);
    int w = wp-1; w = w<0?0:(w>31?31:w);
    p[i] = f2b(x[((size_t)(n*3+c)*32 + h)*32 + w]);
  }
}

// conv1 im2col: padded -> AI[262144][32], k=tap*3+ci, k>=27 zero
__global__ void k_im2col(const u16* __restrict__ xp, u16* __restrict__ AI){
  int m = blockIdx.x*256 + threadIdx.x;
  int w = m & 31; int h = (m>>5)&31; int n = m>>10;
  u16 buf[32];
  #pragma unroll
  for(int j=27;j<32;j++) buf[j]=0;
  #pragma unroll
  for(int tap=0;tap<9;tap++){
    int dh=tap/3, dw=tap-dh*3;
    const u16* s = xp + ((size_t)(n*34 + h+dh)*34 + (w+dw))*3;
    buf[tap*3+0]=s[0]; buf[tap*3+1]=s[1]; buf[tap*3+2]=s[2];
  }
  uint4* d = (uint4*)(AI + (size_t)m*32);
  const uint4* b4 = (const uint4*)buf;
  d[0]=b4[0]; d[1]=b4[1]; d[2]=b4[2]; d[3]=b4[3];
}

// ---------- conv: implicit GEMM MFMA. Block = 64 px x 64 couts, 4 waves (2Mx2N), fp32 out ----------
__global__ __launch_bounds__(256) void k_conv_mfma(
    const u16* __restrict__ xp, const u16* __restrict__ wf, const float* __restrict__ bias,
    float* __restrict__ y, int H, int W, int Cin, int NCT, int R, int coutOff, int yOff, int yC)
{
  extern __shared__ u16 lds[];
  const int Wp = W + 2;
  const int CS = (Cin < 256) ? Cin : 256;
  const int S  = CS + 8;
  const int tid = threadIdx.x;
  const int lane = tid & 63;
  const int wid = tid >> 6;
  const int wm = wid & 1, wn = wid >> 1;
  const int hblocks = H / R;
  const int n  = blockIdx.x / hblocks;
  const int h0 = (blockIdx.x - n*hblocks) * R;
  const int cb64 = coutOff + blockIdx.y * 64;
  const int KTall = Cin >> 5;
  const int wLog = (W==32)?5:((W==16)?4:3);
  const int halves = Cin / CS;

  int offA[2];
  #pragma unroll
  for(int fm=0; fm<2; fm++){
    int p = wm*32 + fm*16 + (lane & 15);
    int rl = p >> wLog; int w_ = p & (W-1);
    offA[fm] = (rl*Wp + w_)*S + ((lane>>4)<<3);
  }
  const int ctb = (cb64>>4) + wn*2;

  f32x4 acc[2][2];
  #pragma unroll
  for(int i=0;i<2;i++){ acc[i][0]=(f32x4){0.f,0.f,0.f,0.f}; acc[i][1]=(f32x4){0.f,0.f,0.f,0.f}; }

  const int csLog = (CS==256)?8:7;
  const int total8 = ((R+2)*Wp*CS) >> 3;

  for(int hv=0; hv<halves; hv++){
    __syncthreads();
    {
      const u16* gx = xp + ((size_t)(n*(H+2) + h0))*(size_t)(Wp*Cin) + (size_t)hv*CS;
      for(int i8=tid; i8<total8; i8+=256){
        int e = i8 << 3; int pix = e >> csLog; int ci = e & (CS-1);
        *(uint4*)(lds + pix*S + ci) = *(const uint4*)(gx + (size_t)pix*Cin + ci);
      }
    }
    __syncthreads();
    const int ktb = (hv*CS) >> 5;
    for(int tap=0; tap<9; tap++){
      const int dh = tap/3, dw = tap - dh*3;
      const u16* lA0 = lds + offA[0] + (dh*Wp + dw)*S;
      const u16* lA1 = lds + offA[1] + (dh*Wp + dw)*S;
      for(int ci0=0; ci0<CS; ci0+=32){
        int kt = tap*KTall + ktb + (ci0>>5);
        const u16* bp = wf + (((size_t)kt*NCT + ctb)*64 + lane)*8;
        bf16x8 b0 = *(const bf16x8*)(bp);
        bf16x8 b1 = *(const bf16x8*)(bp + 512);
        bf16x8 a0 = *(const bf16x8*)(lA0 + ci0);
        bf16x8 a1 = *(const bf16x8*)(lA1 + ci0);
        acc[0][0] = __builtin_amdgcn_mfma_f32_16x16x32_bf16(a0,b0,acc[0][0],0,0,0);
        acc[0][1] = __builtin_amdgcn_mfma_f32_16x16x32_bf16(a0,b1,acc[0][1],0,0,0);
        acc[1][0] = __builtin_amdgcn_mfma_f32_16x16x32_bf16(a1,b0,acc[1][0],0,0,0);
        acc[1][1] = __builtin_amdgcn_mfma_f32_16x16x32_bf16(a1,b1,acc[1][1],0,0,0);
      }
    }
  }
  const int col = lane & 15;
  const int rowq = (lane>>4)<<2;
  #pragma unroll
  for(int fn=0; fn<2; fn++){
    int coutG = cb64 + wn*32 + fn*16 + col;
    float bs = bias[coutG];
    int cl = coutG - yOff;
    #pragma unroll
    for(int fm=0; fm<2; fm++){
      #pragma unroll
      for(int ri=0; ri<4; ri++){
        int p = wm*32 + fm*16 + rowq + ri;
        int rl = p >> wLog; int w_ = p & (W-1);
        y[(((size_t)n*H + h0+rl)*W + w_)*(size_t)yC + cl] = acc[fm][fn][ri] + bs;
      }
    }
  }
}

// ---------- conv1 GEMM over im2col (K=32), fp32 out ----------
__global__ __launch_bounds__(256) void k_gemm_c1(
    const u16* __restrict__ A, const u16* __restrict__ wf, const float* __restrict__ bias,
    float* __restrict__ y, int K, int NCT, int yC, int coutOff, int yOff)
{
  const int tid = threadIdx.x; const int lane = tid & 63; const int wid = tid >> 6;
  const int wm = wid & 1, wn = wid >> 1;
  const int mb = blockIdx.x*64;
  const int col = lane & 15;
  f32x4 acc[2][2];
  #pragma unroll
  for(int i=0;i<2;i++){ acc[i][0]=(f32x4){0.f,0.f,0.f,0.f}; acc[i][1]=(f32x4){0.f,0.f,0.f,0.f}; }
  const u16* a0p = A + (size_t)(mb + wm*32 + col)*K + ((lane>>4)<<3);
  const u16* a1p = a0p + (size_t)16*K;
  const int ct = (coutOff>>4) + wn*2;
  const int KT = K >> 5;
  for(int kt=0; kt<KT; kt++){
    bf16x8 a0 = *(const bf16x8*)(a0p + (size_t)kt*32);
    bf16x8 a1 = *(const bf16x8*)(a1p + (size_t)kt*32);
    const u16* bp = wf + (((size_t)kt*NCT + ct)*64 + lane)*8;
    bf16x8 b0 = *(const bf16x8*)(bp);
    bf16x8 b1 = *(const bf16x8*)(bp + 512);
    acc[0][0] = __builtin_amdgcn_mfma_f32_16x16x32_bf16(a0,b0,acc[0][0],0,0,0);
    acc[0][1] = __builtin_amdgcn_mfma_f32_16x16x32_bf16(a0,b1,acc[0][1],0,0,0);
    acc[1][0] = __builtin_amdgcn_mfma_f32_16x16x32_bf16(a1,b0,acc[1][0],0,0,0);
    acc[1][1] = __builtin_amdgcn_mfma_f32_16x16x32_bf16(a1,b1,acc[1][1],0,0,0);
  }
  const int rowq = (lane>>4)<<2;
  #pragma unroll
  for(int fn=0; fn<2; fn++){
    int coutG = wn*32 + fn*16 + col + coutOff;
    float bs = bias[coutG];
    int cl = coutG - yOff;
    #pragma unroll
    for(int fm=0; fm<2; fm++){
      #pragma unroll
      for(int ri=0; ri<4; ri++){
        int m = mb + wm*32 + fm*16 + rowq + ri;
        y[(size_t)m*yC + cl] = acc[fm][fn][ri] + bs;
      }
    }
  }
}

// ---------- FC GEMM, split-K, fp32 partials (bf16 A x wfrag) ----------
__global__ __launch_bounds__(256) void k_gemm_part(
    const u16* __restrict__ A, const u16* __restrict__ wf, float* __restrict__ P,
    int M, int K, int NCT, int ncp, int KTC)
{
  const int tid = threadIdx.x; const int lane = tid & 63; const int wid = tid >> 6;
  const int wm = wid & 1, wn = wid >> 1;
  const int mb = blockIdx.x*64, nb = blockIdx.y*64, kz = blockIdx.z;
  const int col = lane & 15;
  f32x4 acc[2][2];
  #pragma unroll
  for(int i=0;i<2;i++){ acc[i][0]=(f32x4){0.f,0.f,0.f,0.f}; acc[i][1]=(f32x4){0.f,0.f,0.f,0.f}; }
  const u16* a0p = A + (size_t)(mb + wm*32 + col)*K + ((lane>>4)<<3);
  const u16* a1p = a0p + (size_t)16*K;
  const int kt0 = kz*KTC;
  for(int t=0; t<KTC; t++){
    int kt = kt0 + t;
    bf16x8 a0 = *(const bf16x8*)(a0p + (size_t)kt*32);
    bf16x8 a1 = *(const bf16x8*)(a1p + (size_t)kt*32);
    const u16* bp = wf + (((size_t)kt*NCT + (nb>>4) + wn*2)*64 + lane)*8;
    bf16x8 b0 = *(const bf16x8*)(bp);
    bf16x8 b1 = *(const bf16x8*)(bp + 512);
    acc[0][0] = __builtin_amdgcn_mfma_f32_16x16x32_bf16(a0,b0,acc[0][0],0,0,0);
    acc[0][1] = __builtin_amdgcn_mfma_f32_16x16x32_bf16(a0,b1,acc[0][1],0,0,0);
    acc[1][0] = __builtin_amdgcn_mfma_f32_16x16x32_bf16(a1,b0,acc[1][0],0,0,0);
    acc[1][1] = __builtin_amdgcn_mfma_f32_16x16x32_bf16(a1,b1,acc[1][1],0,0,0);
  }
  const int rowq = (lane>>4)<<2;
  #pragma unroll
  for(int fm=0; fm<2; fm++){
    #pragma unroll
    for(int fn=0; fn<2; fn++){
      #pragma unroll
      for(int ri=0; ri<4; ri++){
        int m = mb + wm*32 + fm*16 + rowq + ri;
        int c = nb + wn*32 + fn*16 + col;
        P[((size_t)kz*M + m)*ncp + c] = acc[fm][fn][ri];
      }
    }
  }
}

// ---------- 2x2 maxpool fp32 NHWC ----------
__global__ void k_pool_f32(const float* __restrict__ in, float* __restrict__ out, int HO, int WO, int C){
  int cpg = C >> 2;
  int total = 256*HO*WO*cpg;
  for(int i = blockIdx.x*256 + threadIdx.x; i < total; i += gridDim.x*256){
    int c4 = i % cpg; int t = i / cpg;
    int wo = t % WO; t /= WO; int ho = t % HO; int n = t / HO;
    const int Wi = 2*WO;
    const float* p = in + (((size_t)(n*2*HO + 2*ho))*Wi + 2*wo)*C + c4*4;
    float4 v00 = *(const float4*)p;
    float4 v01 = *(const float4*)(p + C);
    float4 v10 = *(const float4*)(p + (size_t)Wi*C);
    float4 v11 = *(const float4*)(p + (size_t)Wi*C + C);
    float4 o;
    o.x = fmaxf(fmaxf(v00.x,v01.x), fmaxf(v10.x,v11.x));
    o.y = fmaxf(fmaxf(v00.y,v01.y), fmaxf(v10.y,v11.y));
    o.z = fmaxf(fmaxf(v00.z,v01.z), fmaxf(v10.z,v11.z));
    o.w = fmaxf(fmaxf(v00.w,v01.w), fmaxf(v10.w,v11.w));
    *(float4*)(out + ((size_t)(n*HO + ho)*WO + wo)*C + c4*4) = o;
  }
}

// ---------- per-channel sum/sumsq partials, fp32 input ----------
__global__ __launch_bounds__(256) void k_stats_f32(const float* __restrict__ in, float* __restrict__ part,
                                                   int total, int C, int CH){
  extern __shared__ float ls[];
  const int tid = threadIdx.x; const int b = blockIdx.x;
  const int cpg4 = C >> 2;
  const bool pow2p = ((C & 3)==0) && (cpg4>0) && ((256 % cpg4)==0);
  if(pow2p){
    int total4 = total >> 2;
    int per = ((total4 + CH - 1)/CH + 255) & ~255;
    int s = b*per; int e = s+per; if(e>total4) e=total4;
    float sm[4]={0,0,0,0}, sq[4]={0,0,0,0};
    for(int i=s+tid; i<e; i+=256){
      float4 v = *(const float4*)(in + ((size_t)i<<2));
      sm[0]+=v.x; sq[0]+=v.x*v.x; sm[1]+=v.y; sq[1]+=v.y*v.y;
      sm[2]+=v.z; sq[2]+=v.z*v.z; sm[3]+=v.w; sq[3]+=v.w*v.w;
    }
    #pragma unroll
    for(int j=0;j<4;j++){ ls[tid*8+j]=sm[j]; ls[tid*8+4+j]=sq[j]; }
    __syncthreads();
    int G = 256/cpg4;
    for(int c=tid;c<C;c+=256){
      int c4=c>>2, j=c&3; float ssum=0.f, ssq=0.f;
      for(int g=0; g<G; g++){ int t = g*cpg4 + c4; ssum += ls[t*8+j]; ssq += ls[t*8+4+j]; }
      part[(size_t)b*2*C + c] = ssum; part[(size_t)b*2*C + C + c] = ssq;
    }
  } else if((C & 3)==0){
    for(int i=tid;i<2*C;i+=256) ls[i]=0.f;
    __syncthreads();
    int total4 = total >> 2;
    int per = (total4 + CH - 1)/CH;
    int s = b*per; int e = s+per; if(e>total4) e=total4;
    for(int i=s+tid;i<e;i+=256){
      float4 v = *(const float4*)(in + ((size_t)i<<2));
      int c0 = (i % cpg4)*4;
      atomicAdd(&ls[c0+0], v.x); atomicAdd(&ls[C+c0+0], v.x*v.x);
      atomicAdd(&ls[c0+1], v.y); atomicAdd(&ls[C+c0+1], v.y*v.y);
      atomicAdd(&ls[c0+2], v.z); atomicAdd(&ls[C+c0+2], v.z*v.z);
      atomicAdd(&ls[c0+3], v.w); atomicAdd(&ls[C+c0+3], v.w*v.w);
    }
    __syncthreads();
    for(int c=tid;c<2*C;c+=256) part[(size_t)b*2*C + c] = ls[c];
  } else {
    for(int i=tid;i<2*C;i+=256) ls[i]=0.f;
    __syncthreads();
    int per = (total + CH - 1)/CH;
    int s = b*per; int e = s+per; if(e>total) e=total;
    for(int i=s+tid;i<e;i+=256){
      float v = in[i]; int c = i % C;
      atomicAdd(&ls[c], v); atomicAdd(&ls[C+c], v*v);
    }
    __syncthreads();
    for(int c=tid;c<2*C;c+=256) part[(size_t)b*2*C + c] = ls[c];
  }
}

// reduce partials -> AB[cbase+c]=A, AB[Cfull+cbase+c]=B  (g,bt passed pre-offset)
__global__ void k_bn_prep(const float* __restrict__ part, const float* __restrict__ g,
                          const float* __restrict__ bt, float* __restrict__ AB,
                          int C, int CH, float invCnt, int cbase, int Cfull){
  int c = blockIdx.x*256 + threadIdx.x; if(c>=C) return;
  float s=0.f, q=0.f;
  for(int b=0;b<CH;b++){ s += part[(size_t)b*2*C + c]; q += part[(size_t)b*2*C + C + c]; }
  float m = s*invCnt; float v = q*invCnt - m*m;
  float rs = rsqrtf(v + 1e-5f);
  float A = g[c]*rs;
  AB[cbase+c] = A; AB[Cfull+cbase+c] = bt[c] - m*A;
}

// normalize(fp32 in) + hardtanh + bf16 write (padded-with-edge-replication or flat)
__global__ void k_bn_act_f32(const float* __restrict__ in, const float* __restrict__ Aa,
                             const float* __restrict__ Bb, u16* __restrict__ out,
                             int Cbuf, int rows, int HO, int WO, int Cfull, int cbase,
                             int padMode, int clampF){
  int cpg = Cbuf >> 3;
  int total = rows * cpg;
  for(int i = blockIdx.x*256 + threadIdx.x; i < total; i += gridDim.x*256){
    int c8 = i % cpg; int row = i / cpg; int c0 = c8*8;
    float4 v0 = *(const float4*)(in + (size_t)i*8);
    float4 v1 = *(const float4*)(in + (size_t)i*8 + 4);
    float4 A0 = *(const float4*)(Aa + c0);
    float4 A1 = *(const float4*)(Aa + c0 + 4);
    float4 B0 = *(const float4*)(Bb + c0);
    float4 B1 = *(const float4*)(Bb + c0 + 4);
    float f[8];
    f[0]=v0.x*A0.x+B0.x; f[1]=v0.y*A0.y+B0.y; f[2]=v0.z*A0.z+B0.z; f[3]=v0.w*A0.w+B0.w;
    f[4]=v1.x*A1.x+B1.x; f[5]=v1.y*A1.y+B1.y; f[6]=v1.z*A1.z+B1.z; f[7]=v1.w*A1.w+B1.w;
    if(clampF){
      #pragma unroll
      for(int j=0;j<8;j++) f[j] = fminf(fmaxf(f[j], -1.f), 1.f);
    }
    uint4 o;
    o.x = (u32)f2b(f[0]) | ((u32)f2b(f[1])<<16);
    o.y = (u32)f2b(f[2]) | ((u32)f2b(f[3])<<16);
    o.z = (u32)f2b(f[4]) | ((u32)f2b(f[5])<<16);
    o.w = (u32)f2b(f[6]) | ((u32)f2b(f[7])<<16);
    if(!padMode){
      *(uint4*)(out + (size_t)row*Cbuf + c0) = o;
    } else {
      int w = row % WO; int t = row / WO; int h = t % HO; int n = t / HO;
      int Wp2 = WO + 2;
      size_t base = (size_t)n*(HO+2)*Wp2;
      #define WRP(hp,wp) *(uint4*)(out + ((base + (size_t)(hp)*Wp2 + (wp))*(size_t)Cfull) + cbase + c0) = o
      WRP(h+1, w+1);
      if(h==0)            WRP(0,    w+1);
      if(h==HO-1)         WRP(HO+1, w+1);
      if(w==0)            WRP(h+1,  0);
      if(w==WO-1)         WRP(h+1,  WO+1);
      if(h==0    && w==0)    WRP(0,    0);
      if(h==0    && w==WO-1) WRP(0,    WO+1);
      if(h==HO-1 && w==0)    WRP(HO+1, 0);
      if(h==HO-1 && w==WO-1) WRP(HO+1, WO+1);
      #undef WRP
    }
  }
}

__global__ void k_fc_finish_f32(const float* __restrict__ P, const float* __restrict__ bias,
                                float* __restrict__ y, int M, int Nf, int ncp, int CH){
  int total = M*Nf;
  for(int i = blockIdx.x*256 + threadIdx.x; i < total; i += gridDim.x*256){
    int nf = i % Nf; int m = i / Nf;
    float s = bias[nf];
    for(int z=0; z<CH; z++) s += P[((size_t)z*M + m)*ncp + nf];
    y[i] = s;
  }
}

__global__ void k_final(const float* __restrict__ y, const float* __restrict__ AB,
                        float* __restrict__ out, int C, int total){
  for(int i = blockIdx.x*256 + threadIdx.x; i < total; i += gridDim.x*256){
    int c = i % C;
    out[i] = y[i]*AB[c] + AB[C+c];
  }
}

// ================= host =================
extern "C" void kernel_launch(void* const* d_in, const int* in_sizes, int n_in,
                              void* d_out, int out_size, void* d_ws, size_t ws_size,
                              hipStream_t stream) {
  (void)in_sizes; (void)n_in; (void)out_size; (void)ws_size;
  const float* x = (const float*)d_in[0];
  const float *cw[6], *cb[6], *cgam[6], *cbt[6];
  for(int i=0;i<6;i++){
    cw[i]  =(const float*)d_in[1+4*i];
    cb[i]  =(const float*)d_in[2+4*i];
    cgam[i]=(const float*)d_in[3+4*i];
    cbt[i] =(const float*)d_in[4+4*i];
  }
  const float *fw[3], *fbias[3], *fg[3], *fbt[3];
  for(int i=0;i<3;i++){
    fw[i]   =(const float*)d_in[25+4*i];
    fbias[i]=(const float*)d_in[26+4*i];
    fg[i]   =(const float*)d_in[27+4*i];
    fbt[i]  =(const float*)d_in[28+4*i];
  }

  char* ws = (char*)d_ws;
  size_t off = 0;
  auto alloc = [&](size_t bytes){ size_t o = off; off = (off + bytes + 255) & ~(size_t)255; return o; };
  const size_t oX  = alloc((size_t)256*34*34*3*2);        // padded input bf16, 1.78MB
  const size_t oP  = alloc((size_t)256*34*34*128*2);      // padded acts A (75.8MB); later FC wfrags
  const size_t oP2 = alloc((size_t)256*18*18*128*2);      // padded acts B (21.2MB)
  const size_t oYf = alloc((size_t)67108864);             // fp32 pre-BN (67.1MB); later FC bufs
  const size_t oQf = alloc((size_t)16777216);             // fp32 pooled (16.8MB); first holds AI bf16
  const int CinA[6]  = {3,128,128,256,256,512};
  const int CoutA[6] = {128,128,256,256,512,512};
  const int KTA[6]   = {1,36,36,72,72,144};
  size_t oWc[6];
  for(int l=0;l<6;l++) oWc[l] = alloc((size_t)KTA[l]*(CoutA[l]>>4)*512*2);
  const size_t oSP = alloc((size_t)256*2*1536*4);
  const size_t oAB = alloc((size_t)2*1536*4);

  u16*   X    = (u16*)(ws + oX);
  u16*   Pb   = (u16*)(ws + oP);
  u16*   P2   = (u16*)(ws + oP2);
  float* Yf   = (float*)(ws + oYf);
  float* Qf   = (float*)(ws + oQf);
  u16*   AI   = (u16*)(ws + oQf);                       // 16.78MB exactly, dead before pools
  float* SP   = (float*)(ws + oSP);
  float* AB   = (float*)(ws + oAB);
  // FC buffers in oYf (dead after conv6 pool):
  u16*   F0   = (u16*)(ws + oYf);                        // 256x8192 bf16 (4.2MB)
  float* FA32 = (float*)(ws + oYf + (size_t)8*1024*1024);
  u16*   FAa  = (u16*)(ws + oYf + (size_t)10*1024*1024);
  float* FB32 = (float*)(ws + oYf + (size_t)12*1024*1024);
  u16*   FBa  = (u16*)(ws + oYf + (size_t)14*1024*1024);
  float* F3f  = (float*)(ws + oYf + (size_t)16*1024*1024);
  float* Pg   = (float*)(ws + oYf + (size_t)20*1024*1024);
  // FC weight fragments in oP (dead after conv6 conv):
  u16* Wf1 = (u16*)(ws + oP);
  u16* Wf2 = (u16*)(ws + oP + (size_t)26*1024*1024);
  u16* Wf3 = (u16*)(ws + oP + (size_t)31*1024*1024);

  for(int l=0;l<6;l++)
    k_prep_wfrag_conv<<<1024,256,0,stream>>>(cw[l], (u16*)(ws+oWc[l]), CoutA[l], CinA[l], KTA[l]);
  k_pad_input<<<2048,256,0,stream>>>(x, X);
  k_im2col<<<1024,256,0,stream>>>(X, AI);

  // ---- conv1: two 64-channel halves, fp32 pre-BN ----
  for(int h=0; h<2; h++){
    k_gemm_c1<<<4096,256,0,stream>>>(AI, (u16*)(ws+oWc[0]), cb[0], Yf, 32, 8, 64, h*64, h*64);
    k_stats_f32<<<256,256,8192,stream>>>(Yf, SP, 262144*64, 64, 256);
    k_bn_prep<<<1,256,0,stream>>>(SP, cgam[0]+h*64, cbt[0]+h*64, AB, 64, 256, 1.0f/262144.0f, h*64, 128);
    k_bn_act_f32<<<2048,256,0,stream>>>(Yf, AB+h*64, AB+128+h*64, Pb, 64, 262144, 32, 32, 128, h*64, 1, 1);
  }
  // ---- conv2: halves, pool, in Pb -> out P2 ----
  for(int h=0; h<2; h++){
    k_conv_mfma<<<dim3(4096,1),256,36992,stream>>>(Pb, (u16*)(ws+oWc[1]), cb[1], Yf, 32,32,128, 8, 2, h*64, h*64, 64);
    k_pool_f32<<<2048,256,0,stream>>>(Yf, Qf, 16, 16, 64);
    k_stats_f32<<<256,256,8192,stream>>>(Qf, SP, 65536*64, 64, 256);
    k_bn_prep<<<1,256,0,stream>>>(SP, cgam[1]+h*64, cbt[1]+h*64, AB, 64, 256, 1.0f/65536.0f, h*64, 128);
    k_bn_act_f32<<<2048,256,0,stream>>>(Qf, AB+h*64, AB+128+h*64, P2, 64, 65536, 16, 16, 128, h*64, 1, 1);
  }
  // ---- conv3: full, in P2 -> out Pb ----
  k_conv_mfma<<<dim3(1024,4),256,29376,stream>>>(P2, (u16*)(ws+oWc[2]), cb[2], Yf, 16,16,128, 16, 4, 0,0, 256);
  k_stats_f32<<<256,256,8192,stream>>>(Yf, SP, 65536*256, 256, 256);
  k_bn_prep<<<1,256,0,stream>>>(SP, cgam[2], cbt[2], AB, 256, 256, 1.0f/65536.0f, 0, 256);
  k_bn_act_f32<<<2048,256,0,stream>>>(Yf, AB, AB+256, Pb, 256, 65536, 16, 16, 256, 0, 1, 1);
  // ---- conv4: full, pool, in Pb -> out P2 ----
  k_conv_mfma<<<dim3(1024,4),256,57024,stream>>>(Pb, (u16*)(ws+oWc[3]), cb[3], Yf, 16,16,256, 16, 4, 0,0, 256);
  k_pool_f32<<<2048,256,0,stream>>>(Yf, Qf, 8, 8, 256);
  k_stats_f32<<<256,256,8192,stream>>>(Qf, SP, 16384*256, 256, 256);
  k_bn_prep<<<1,256,0,stream>>>(SP, cgam[3], cbt[3], AB, 256, 256, 1.0f/16384.0f, 0, 256);
  k_bn_act_f32<<<2048,256,0,stream>>>(Qf, AB, AB+256, P2, 256, 16384, 8, 8, 256, 0, 1, 1);
  // ---- conv5: full, in P2 -> out Pb ----
  k_conv_mfma<<<dim3(256,8),256,52800,stream>>>(P2, (u16*)(ws+oWc[4]), cb[4], Yf, 8,8,256, 32, 8, 0,0, 512);
  k_stats_f32<<<256,256,8192,stream>>>(Yf, SP, 16384*512, 512, 256);
  k_bn_prep<<<2,256,0,stream>>>(SP, cgam[4], cbt[4], AB, 512, 256, 1.0f/16384.0f, 0, 512);
  k_bn_act_f32<<<2048,256,0,stream>>>(Yf, AB, AB+512, Pb, 512, 16384, 8, 8, 512, 0, 1, 1);
  // ---- conv6: full, pool, in Pb -> out F0 (flat) ----
  k_conv_mfma<<<dim3(256,8),256,52800,stream>>>(Pb, (u16*)(ws+oWc[5]), cb[5], Yf, 8,8,512, 32, 8, 0,0, 512);
  k_pool_f32<<<2048,256,0,stream>>>(Yf, Qf, 4, 4, 512);
  k_stats_f32<<<256,256,8192,stream>>>(Qf, SP, 4096*512, 512, 256);
  k_bn_prep<<<2,256,0,stream>>>(SP, cgam[5], cbt[5], AB, 512, 256, 1.0f/4096.0f, 0, 512);
  k_bn_act_f32<<<512,256,0,stream>>>(Qf, AB, AB+512, F0, 512, 4096, 4, 4, 512, 0, 0, 1);

  // ---- FC weight fragments (oP is dead now) ----
  k_prep_wfrag_fc<<<2048,256,0,stream>>>(fw[0], Wf1, 1536, 8192, 96, 1);
  k_prep_wfrag_fc<<<1024,256,0,stream>>>(fw[1], Wf2, 1536, 1536, 96, 0);
  k_prep_wfrag_fc<<<64,256,0,stream>>>  (fw[2], Wf3, 10,   1536, 4,  0);

  // FC1
  k_gemm_part<<<dim3(4,24,4),256,0,stream>>>(F0, Wf1, Pg, 256, 8192, 96, 1536, 64);
  k_fc_finish_f32<<<768,256,0,stream>>>(Pg, fbias[0], FA32, 256, 1536, 1536, 4);
  k_stats_f32<<<16,256,12288,stream>>>(FA32, SP, 256*1536, 1536, 16);
  k_bn_prep<<<6,256,0,stream>>>(SP, fg[0], fbt[0], AB, 1536, 16, 1.0f/256.0f, 0, 1536);
  k_bn_act_f32<<<256,256,0,stream>>>(FA32, AB, AB+1536, FAa, 1536, 256, 0,0, 1536, 0, 0, 1);
  // FC2
  k_gemm_part<<<dim3(4,24,4),256,0,stream>>>(FAa, Wf2, Pg, 256, 1536, 96, 1536, 12);
  k_fc_finish_f32<<<768,256,0,stream>>>(Pg, fbias[1], FB32, 256, 1536, 1536, 4);
  k_stats_f32<<<16,256,12288,stream>>>(FB32, SP, 256*1536, 1536, 16);
  k_bn_prep<<<6,256,0,stream>>>(SP, fg[1], fbt[1], AB, 1536, 16, 1.0f/256.0f, 0, 1536);
  k_bn_act_f32<<<256,256,0,stream>>>(FB32, AB, AB+1536, FBa, 1536, 256, 0,0, 1536, 0, 0, 1);
  // FC3 (N padded to 64) -> BN (no clamp) -> f32 out
  k_gemm_part<<<dim3(4,1,4),256,0,stream>>>(FBa, Wf3, Pg, 256, 1536, 4, 64, 12);
  k_fc_finish_f32<<<16,256,0,stream>>>(Pg, fbias[2], F3f, 256, 10, 64, 4);
  k_stats_f32<<<4,256,256,stream>>>(F3f, SP, 2560, 10, 4);
  k_bn_prep<<<1,256,0,stream>>>(SP, fg[2], fbt[2], AB, 10, 4, 1.0f/256.0f, 0, 10);
  k_final<<<10,256,0,stream>>>(F3f, AB, (float*)d_out, 10, 2560);
}

// Round 4
// 1828.641 us; speedup vs baseline: 4.1174x; 1.0999x over previous
//
#include <hip/hip_runtime.h>
#include <stdint.h>

typedef unsigned short u16;
typedef unsigned int   u32;
typedef __attribute__((ext_vector_type(8))) short bf16x8;
typedef __attribute__((ext_vector_type(4))) float f32x4;

__device__ __forceinline__ float b2f(u16 u){ u32 i = ((u32)u) << 16; float f; __builtin_memcpy(&f,&i,4); return f; }
__device__ __forceinline__ u16 f2b(float f){ u32 i; __builtin_memcpy(&i,&f,4); i += 0x7FFFu + ((i>>16)&1u); return (u16)(i>>16); }

// ---------- weight prep: MFMA B-fragment layout ----------
__global__ void k_prep_wfrag_conv(const float* __restrict__ w, u16* __restrict__ wf,
                                  int Cout, int Cin, int KT){
  int NCT = Cout >> 4;
  int total = KT*NCT*512;
  int Kmax = 9*Cin;
  for(int i = blockIdx.x*256 + threadIdx.x; i < total; i += gridDim.x*256){
    int i8 = i & 7; int lane = (i>>3)&63; int t = i>>9;
    int ct = t % NCT; int kt = t / NCT;
    int k = kt*32 + ((lane>>4)<<3) + i8;
    int co = (ct<<4) + (lane&15);
    u16 v = 0;
    if(k < Kmax){
      int tap = k / Cin; int ci = k - tap*Cin;
      v = (w[(size_t)(co*Cin+ci)*9 + tap] >= 0.f) ? (u16)0x3F80 : (u16)0xBF80;
    }
    wf[i] = v;
  }
}
__global__ void k_prep_wfrag_fc(const float* __restrict__ w, u16* __restrict__ wf,
                                int Nf, int K, int NCTp, int permute){
  int total = (K>>5)*NCTp*512;
  for(int i = blockIdx.x*256 + threadIdx.x; i < total; i += gridDim.x*256){
    int i8 = i & 7; int lane = (i>>3)&63; int t = i>>9;
    int ct = t % NCTp; int kt = t / NCTp;
    int k = kt*32 + ((lane>>4)<<3) + i8;
    int n = (ct<<4) + (lane&15);
    u16 v = 0;
    if(n < Nf){
      int kr = permute ? ((k & 511)*16 + (k >> 9)) : k;
      v = (w[(size_t)n*K + kr] >= 0.f) ? (u16)0x3F80 : (u16)0xBF80;
    }
    wf[i] = v;
  }
}

// x (256,3,32,32) f32 NCHW -> (256,34,34,3) bf16 NHWC edge-padded
__global__ void k_pad_input(const float* __restrict__ x, u16* __restrict__ p){
  int total = 256*34*34*3;
  for(int i = blockIdx.x*256 + threadIdx.x; i < total; i += gridDim.x*256){
    int c = i % 3; int t = i / 3; int wp = t % 34; t /= 34; int hp = t % 34; int n = t / 34;
    int h = hp-1; h = h<0?0:(h>31?31:h);
    int w = wp-1; w = w<0?0:(w>31?31:w);
    p[i] = f2b(x[((size_t)(n*3+c)*32 + h)*32 + w]);
  }
}

// conv1 im2col: padded -> AI[262144][32], k=tap*3+ci, k>=27 zero
__global__ void k_im2col(const u16* __restrict__ xp, u16* __restrict__ AI){
  int m = blockIdx.x*256 + threadIdx.x;
  int w = m & 31; int h = (m>>5)&31; int n = m>>10;
  u16 buf[32];
  #pragma unroll
  for(int j=27;j<32;j++) buf[j]=0;
  #pragma unroll
  for(int tap=0;tap<9;tap++){
    int dh=tap/3, dw=tap-dh*3;
    const u16* s = xp + ((size_t)(n*34 + h+dh)*34 + (w+dw))*3;
    buf[tap*3+0]=s[0]; buf[tap*3+1]=s[1]; buf[tap*3+2]=s[2];
  }
  uint4* d = (uint4*)(AI + (size_t)m*32);
  const uint4* b4 = (const uint4*)buf;
  d[0]=b4[0]; d[1]=b4[1]; d[2]=b4[2]; d[3]=b4[3];
}

// ---------- conv: implicit GEMM MFMA, templated tile. 4 waves (2Mx2N), fp32 out ----------
// block tile: (2*MF*16) px  x  (2*NF*16) couts ; per wave MF*NF MFMAs per K-step of 32
template<int MF,int NF,int CS>
__global__ __launch_bounds__(256) void k_conv_mfma_t(
    const u16* __restrict__ xp, const u16* __restrict__ wf, const float* __restrict__ bias,
    float* __restrict__ y, int H, int W, int Cin, int NCT, int R, int coutOff, int yOff, int yC)
{
  extern __shared__ u16 lds[];
  const int Wp = W + 2;
  const int S  = CS + 8;
  const int tid = threadIdx.x;
  const int lane = tid & 63;
  const int wid = tid >> 6;
  const int wm = wid & 1, wn = wid >> 1;
  const int hblocks = H / R;
  const int n  = blockIdx.x / hblocks;
  const int h0 = (blockIdx.x - n*hblocks) * R;
  const int cb = coutOff + blockIdx.y * (2*NF*16);
  const int KTall = Cin >> 5;
  const int wLog = (W==32)?5:((W==16)?4:3);
  const int halves = Cin / CS;

  int offA[MF];
  #pragma unroll
  for(int fm=0; fm<MF; fm++){
    int p = (wm*MF+fm)*16 + (lane & 15);
    int rl = p >> wLog; int w_ = p & (W-1);
    offA[fm] = (rl*Wp + w_)*S + ((lane>>4)<<3);
  }
  const int ctb = (cb>>4) + wn*NF;

  f32x4 acc[MF][NF];
  #pragma unroll
  for(int i=0;i<MF;i++)
    #pragma unroll
    for(int j=0;j<NF;j++) acc[i][j] = (f32x4){0.f,0.f,0.f,0.f};

  const int csLog = (CS==256)?8:7;
  const int total8 = ((R+2)*Wp*CS) >> 3;

  for(int hv=0; hv<halves; hv++){
    __syncthreads();
    {
      const u16* gx = xp + ((size_t)(n*(H+2) + h0))*(size_t)(Wp*Cin) + (size_t)hv*CS;
      for(int i8=tid; i8<total8; i8+=256){
        int e = i8 << 3; int pix = e >> csLog; int ci = e & (CS-1);
        *(uint4*)(lds + pix*S + ci) = *(const uint4*)(gx + (size_t)pix*Cin + ci);
      }
    }
    __syncthreads();
    const int ktb = (hv*CS) >> 5;
    for(int tap=0; tap<9; tap++){
      const int dh = tap/3, dw = tap - dh*3;
      const int toff = (dh*Wp + dw)*S;
      #pragma unroll 4
      for(int c32=0; c32<(CS>>5); c32++){
        int kt = tap*KTall + ktb + c32;
        const u16* bp = wf + (((size_t)kt*NCT + ctb)*64 + lane)*8;
        bf16x8 bfr[NF];
        #pragma unroll
        for(int fn=0;fn<NF;fn++) bfr[fn] = *(const bf16x8*)(bp + fn*512);
        bf16x8 afr[MF];
        #pragma unroll
        for(int fm=0;fm<MF;fm++) afr[fm] = *(const bf16x8*)(lds + offA[fm] + toff + c32*32);
        #pragma unroll
        for(int fm=0;fm<MF;fm++)
          #pragma unroll
          for(int fn=0;fn<NF;fn++)
            acc[fm][fn] = __builtin_amdgcn_mfma_f32_16x16x32_bf16(afr[fm],bfr[fn],acc[fm][fn],0,0,0);
      }
    }
  }
  const int col = lane & 15;
  const int rowq = (lane>>4)<<2;
  #pragma unroll
  for(int fn=0; fn<NF; fn++){
    int coutG = cb + (wn*NF+fn)*16 + col;
    float bs = bias[coutG];
    int cl = coutG - yOff;
    #pragma unroll
    for(int fm=0; fm<MF; fm++){
      #pragma unroll
      for(int ri=0; ri<4; ri++){
        int p = (wm*MF+fm)*16 + rowq + ri;
        int rl = p >> wLog; int w_ = p & (W-1);
        y[(((size_t)n*H + h0+rl)*W + w_)*(size_t)yC + cl] = acc[fm][fn][ri] + bs;
      }
    }
  }
}

// ---------- conv1 GEMM over im2col (K=32), fp32 out ----------
__global__ __launch_bounds__(256) void k_gemm_c1(
    const u16* __restrict__ A, const u16* __restrict__ wf, const float* __restrict__ bias,
    float* __restrict__ y, int K, int NCT, int yC, int coutOff, int yOff)
{
  const int tid = threadIdx.x; const int lane = tid & 63; const int wid = tid >> 6;
  const int wm = wid & 1, wn = wid >> 1;
  const int mb = blockIdx.x*64;
  const int col = lane & 15;
  f32x4 acc[2][2];
  #pragma unroll
  for(int i=0;i<2;i++){ acc[i][0]=(f32x4){0.f,0.f,0.f,0.f}; acc[i][1]=(f32x4){0.f,0.f,0.f,0.f}; }
  const u16* a0p = A + (size_t)(mb + wm*32 + col)*K + ((lane>>4)<<3);
  const u16* a1p = a0p + (size_t)16*K;
  const int ct = (coutOff>>4) + wn*2;
  const int KT = K >> 5;
  for(int kt=0; kt<KT; kt++){
    bf16x8 a0 = *(const bf16x8*)(a0p + (size_t)kt*32);
    bf16x8 a1 = *(const bf16x8*)(a1p + (size_t)kt*32);
    const u16* bp = wf + (((size_t)kt*NCT + ct)*64 + lane)*8;
    bf16x8 b0 = *(const bf16x8*)(bp);
    bf16x8 b1 = *(const bf16x8*)(bp + 512);
    acc[0][0] = __builtin_amdgcn_mfma_f32_16x16x32_bf16(a0,b0,acc[0][0],0,0,0);
    acc[0][1] = __builtin_amdgcn_mfma_f32_16x16x32_bf16(a0,b1,acc[0][1],0,0,0);
    acc[1][0] = __builtin_amdgcn_mfma_f32_16x16x32_bf16(a1,b0,acc[1][0],0,0,0);
    acc[1][1] = __builtin_amdgcn_mfma_f32_16x16x32_bf16(a1,b1,acc[1][1],0,0,0);
  }
  const int rowq = (lane>>4)<<2;
  #pragma unroll
  for(int fn=0; fn<2; fn++){
    int coutG = wn*32 + fn*16 + col + coutOff;
    float bs = bias[coutG];
    int cl = coutG - yOff;
    #pragma unroll
    for(int fm=0; fm<2; fm++){
      #pragma unroll
      for(int ri=0; ri<4; ri++){
        int m = mb + wm*32 + fm*16 + rowq + ri;
        y[(size_t)m*yC + cl] = acc[fm][fn][ri] + bs;
      }
    }
  }
}

// ---------- FC GEMM, split-K, fp32 partials (bf16 A x wfrag) ----------
__global__ __launch_bounds__(256) void k_gemm_part(
    const u16* __restrict__ A, const u16* __restrict__ wf, float* __restrict__ P,
    int M, int K, int NCT, int ncp, int KTC)
{
  const int tid = threadIdx.x; const int lane = tid & 63; const int wid = tid >> 6;
  const int wm = wid & 1, wn = wid >> 1;
  const int mb = blockIdx.x*64, nb = blockIdx.y*64, kz = blockIdx.z;
  const int col = lane & 15;
  f32x4 acc[2][2];
  #pragma unroll
  for(int i=0;i<2;i++){ acc[i][0]=(f32x4){0.f,0.f,0.f,0.f}; acc[i][1]=(f32x4){0.f,0.f,0.f,0.f}; }
  const u16* a0p = A + (size_t)(mb + wm*32 + col)*K + ((lane>>4)<<3);
  const u16* a1p = a0p + (size_t)16*K;
  const int kt0 = kz*KTC;
  for(int t=0; t<KTC; t++){
    int kt = kt0 + t;
    bf16x8 a0 = *(const bf16x8*)(a0p + (size_t)kt*32);
    bf16x8 a1 = *(const bf16x8*)(a1p + (size_t)kt*32);
    const u16* bp = wf + (((size_t)kt*NCT + (nb>>4) + wn*2)*64 + lane)*8;
    bf16x8 b0 = *(const bf16x8*)(bp);
    bf16x8 b1 = *(const bf16x8*)(bp + 512);
    acc[0][0] = __builtin_amdgcn_mfma_f32_16x16x32_bf16(a0,b0,acc[0][0],0,0,0);
    acc[0][1] = __builtin_amdgcn_mfma_f32_16x16x32_bf16(a0,b1,acc[0][1],0,0,0);
    acc[1][0] = __builtin_amdgcn_mfma_f32_16x16x32_bf16(a1,b0,acc[1][0],0,0,0);
    acc[1][1] = __builtin_amdgcn_mfma_f32_16x16x32_bf16(a1,b1,acc[1][1],0,0,0);
  }
  const int rowq = (lane>>4)<<2;
  #pragma unroll
  for(int fm=0; fm<2; fm++){
    #pragma unroll
    for(int fn=0; fn<2; fn++){
      #pragma unroll
      for(int ri=0; ri<4; ri++){
        int m = mb + wm*32 + fm*16 + rowq + ri;
        int c = nb + wn*32 + fn*16 + col;
        P[((size_t)kz*M + m)*ncp + c] = acc[fm][fn][ri];
      }
    }
  }
}

// ---------- 2x2 maxpool fp32 NHWC ----------
__global__ void k_pool_f32(const float* __restrict__ in, float* __restrict__ out, int HO, int WO, int C){
  int cpg = C >> 2;
  int total = 256*HO*WO*cpg;
  for(int i = blockIdx.x*256 + threadIdx.x; i < total; i += gridDim.x*256){
    int c4 = i % cpg; int t = i / cpg;
    int wo = t % WO; t /= WO; int ho = t % HO; int n = t / HO;
    const int Wi = 2*WO;
    const float* p = in + (((size_t)(n*2*HO + 2*ho))*Wi + 2*wo)*C + c4*4;
    float4 v00 = *(const float4*)p;
    float4 v01 = *(const float4*)(p + C);
    float4 v10 = *(const float4*)(p + (size_t)Wi*C);
    float4 v11 = *(const float4*)(p + (size_t)Wi*C + C);
    float4 o;
    o.x = fmaxf(fmaxf(v00.x,v01.x), fmaxf(v10.x,v11.x));
    o.y = fmaxf(fmaxf(v00.y,v01.y), fmaxf(v10.y,v11.y));
    o.z = fmaxf(fmaxf(v00.z,v01.z), fmaxf(v10.z,v11.z));
    o.w = fmaxf(fmaxf(v00.w,v01.w), fmaxf(v10.w,v11.w));
    *(float4*)(out + ((size_t)(n*HO + ho)*WO + wo)*C + c4*4) = o;
  }
}

// ---------- per-channel sum/sumsq partials, fp32 input ----------
__global__ __launch_bounds__(256) void k_stats_f32(const float* __restrict__ in, float* __restrict__ part,
                                                   int total, int C, int CH){
  extern __shared__ float ls[];
  const int tid = threadIdx.x; const int b = blockIdx.x;
  const int cpg4 = C >> 2;
  const bool pow2p = ((C & 3)==0) && (cpg4>0) && ((256 % cpg4)==0);
  if(pow2p){
    int total4 = total >> 2;
    int per = ((total4 + CH - 1)/CH + 255) & ~255;
    int s = b*per; int e = s+per; if(e>total4) e=total4;
    float sm[4]={0,0,0,0}, sq[4]={0,0,0,0};
    for(int i=s+tid; i<e; i+=256){
      float4 v = *(const float4*)(in + ((size_t)i<<2));
      sm[0]+=v.x; sq[0]+=v.x*v.x; sm[1]+=v.y; sq[1]+=v.y*v.y;
      sm[2]+=v.z; sq[2]+=v.z*v.z; sm[3]+=v.w; sq[3]+=v.w*v.w;
    }
    #pragma unroll
    for(int j=0;j<4;j++){ ls[tid*8+j]=sm[j]; ls[tid*8+4+j]=sq[j]; }
    __syncthreads();
    int G = 256/cpg4;
    for(int c=tid;c<C;c+=256){
      int c4=c>>2, j=c&3; float ssum=0.f, ssq=0.f;
      for(int g=0; g<G; g++){ int t = g*cpg4 + c4; ssum += ls[t*8+j]; ssq += ls[t*8+4+j]; }
      part[(size_t)b*2*C + c] = ssum; part[(size_t)b*2*C + C + c] = ssq;
    }
  } else if((C & 3)==0){
    for(int i=tid;i<2*C;i+=256) ls[i]=0.f;
    __syncthreads();
    int total4 = total >> 2;
    int per = (total4 + CH - 1)/CH;
    int s = b*per; int e = s+per; if(e>total4) e=total4;
    for(int i=s+tid;i<e;i+=256){
      float4 v = *(const float4*)(in + ((size_t)i<<2));
      int c0 = (i % cpg4)*4;
      atomicAdd(&ls[c0+0], v.x); atomicAdd(&ls[C+c0+0], v.x*v.x);
      atomicAdd(&ls[c0+1], v.y); atomicAdd(&ls[C+c0+1], v.y*v.y);
      atomicAdd(&ls[c0+2], v.z); atomicAdd(&ls[C+c0+2], v.z*v.z);
      atomicAdd(&ls[c0+3], v.w); atomicAdd(&ls[C+c0+3], v.w*v.w);
    }
    __syncthreads();
    for(int c=tid;c<2*C;c+=256) part[(size_t)b*2*C + c] = ls[c];
  } else {
    for(int i=tid;i<2*C;i+=256) ls[i]=0.f;
    __syncthreads();
    int per = (total + CH - 1)/CH;
    int s = b*per; int e = s+per; if(e>total) e=total;
    for(int i=s+tid;i<e;i+=256){
      float v = in[i]; int c = i % C;
      atomicAdd(&ls[c], v); atomicAdd(&ls[C+c], v*v);
    }
    __syncthreads();
    for(int c=tid;c<2*C;c+=256) part[(size_t)b*2*C + c] = ls[c];
  }
}

// reduce partials -> AB[cbase+c]=A, AB[Cfull+cbase+c]=B
__global__ void k_bn_prep(const float* __restrict__ part, const float* __restrict__ g,
                          const float* __restrict__ bt, float* __restrict__ AB,
                          int C, int CH, float invCnt, int cbase, int Cfull){
  int c = blockIdx.x*256 + threadIdx.x; if(c>=C) return;
  float s=0.f, q=0.f;
  for(int b=0;b<CH;b++){ s += part[(size_t)b*2*C + c]; q += part[(size_t)b*2*C + C + c]; }
  float m = s*invCnt; float v = q*invCnt - m*m;
  float rs = rsqrtf(v + 1e-5f);
  float A = g[c]*rs;
  AB[cbase+c] = A; AB[Cfull+cbase+c] = bt[c] - m*A;
}

// normalize(fp32 in) + hardtanh + bf16 write (padded-with-edge-replication or flat)
__global__ void k_bn_act_f32(const float* __restrict__ in, const float* __restrict__ Aa,
                             const float* __restrict__ Bb, u16* __restrict__ out,
                             int Cbuf, int rows, int HO, int WO, int Cfull, int cbase,
                             int padMode, int clampF){
  int cpg = Cbuf >> 3;
  int total = rows * cpg;
  for(int i = blockIdx.x*256 + threadIdx.x; i < total; i += gridDim.x*256){
    int c8 = i % cpg; int row = i / cpg; int c0 = c8*8;
    float4 v0 = *(const float4*)(in + (size_t)i*8);
    float4 v1 = *(const float4*)(in + (size_t)i*8 + 4);
    float4 A0 = *(const float4*)(Aa + c0);
    float4 A1 = *(const float4*)(Aa + c0 + 4);
    float4 B0 = *(const float4*)(Bb + c0);
    float4 B1 = *(const float4*)(Bb + c0 + 4);
    float f[8];
    f[0]=v0.x*A0.x+B0.x; f[1]=v0.y*A0.y+B0.y; f[2]=v0.z*A0.z+B0.z; f[3]=v0.w*A0.w+B0.w;
    f[4]=v1.x*A1.x+B1.x; f[5]=v1.y*A1.y+B1.y; f[6]=v1.z*A1.z+B1.z; f[7]=v1.w*A1.w+B1.w;
    if(clampF){
      #pragma unroll
      for(int j=0;j<8;j++) f[j] = fminf(fmaxf(f[j], -1.f), 1.f);
    }
    uint4 o;
    o.x = (u32)f2b(f[0]) | ((u32)f2b(f[1])<<16);
    o.y = (u32)f2b(f[2]) | ((u32)f2b(f[3])<<16);
    o.z = (u32)f2b(f[4]) | ((u32)f2b(f[5])<<16);
    o.w = (u32)f2b(f[6]) | ((u32)f2b(f[7])<<16);
    if(!padMode){
      *(uint4*)(out + (size_t)row*Cbuf + c0) = o;
    } else {
      int w = row % WO; int t = row / WO; int h = t % HO; int n = t / HO;
      int Wp2 = WO + 2;
      size_t base = (size_t)n*(HO+2)*Wp2;
      #define WRP(hp,wp) *(uint4*)(out + ((base + (size_t)(hp)*Wp2 + (wp))*(size_t)Cfull) + cbase + c0) = o
      WRP(h+1, w+1);
      if(h==0)            WRP(0,    w+1);
      if(h==HO-1)         WRP(HO+1, w+1);
      if(w==0)            WRP(h+1,  0);
      if(w==WO-1)         WRP(h+1,  WO+1);
      if(h==0    && w==0)    WRP(0,    0);
      if(h==0    && w==WO-1) WRP(0,    WO+1);
      if(h==HO-1 && w==0)    WRP(HO+1, 0);
      if(h==HO-1 && w==WO-1) WRP(HO+1, WO+1);
      #undef WRP
    }
  }
}

__global__ void k_fc_finish_f32(const float* __restrict__ P, const float* __restrict__ bias,
                                float* __restrict__ y, int M, int Nf, int ncp, int CH){
  int total = M*Nf;
  for(int i = blockIdx.x*256 + threadIdx.x; i < total; i += gridDim.x*256){
    int nf = i % Nf; int m = i / Nf;
    float s = bias[nf];
    for(int z=0; z<CH; z++) s += P[((size_t)z*M + m)*ncp + nf];
    y[i] = s;
  }
}

__global__ void k_final(const float* __restrict__ y, const float* __restrict__ AB,
                        float* __restrict__ out, int C, int total){
  for(int i = blockIdx.x*256 + threadIdx.x; i < total; i += gridDim.x*256){
    int c = i % C;
    out[i] = y[i]*AB[c] + AB[C+c];
  }
}

// ================= host =================
extern "C" void kernel_launch(void* const* d_in, const int* in_sizes, int n_in,
                              void* d_out, int out_size, void* d_ws, size_t ws_size,
                              hipStream_t stream) {
  (void)in_sizes; (void)n_in; (void)out_size; (void)ws_size;
  const float* x = (const float*)d_in[0];
  const float *cw[6], *cb[6], *cgam[6], *cbt[6];
  for(int i=0;i<6;i++){
    cw[i]  =(const float*)d_in[1+4*i];
    cb[i]  =(const float*)d_in[2+4*i];
    cgam[i]=(const float*)d_in[3+4*i];
    cbt[i] =(const float*)d_in[4+4*i];
  }
  const float *fw[3], *fbias[3], *fg[3], *fbt[3];
  for(int i=0;i<3;i++){
    fw[i]   =(const float*)d_in[25+4*i];
    fbias[i]=(const float*)d_in[26+4*i];
    fg[i]   =(const float*)d_in[27+4*i];
    fbt[i]  =(const float*)d_in[28+4*i];
  }

  char* ws = (char*)d_ws;
  size_t off = 0;
  auto alloc = [&](size_t bytes){ size_t o = off; off = (off + bytes + 255) & ~(size_t)255; return o; };
  const size_t oX  = alloc((size_t)256*34*34*3*2);        // padded input bf16
  const size_t oP  = alloc((size_t)256*34*34*128*2);      // padded acts A (75.8MB); later FC wfrags
  const size_t oP2 = alloc((size_t)256*18*18*128*2);      // padded acts B (21.2MB)
  const size_t oYf = alloc((size_t)67108864);             // fp32 pre-BN (67.1MB); later FC bufs
  const size_t oQf = alloc((size_t)16777216);             // fp32 pooled (16.8MB); first holds AI bf16
  const int CinA[6]  = {3,128,128,256,256,512};
  const int CoutA[6] = {128,128,256,256,512,512};
  const int KTA[6]   = {1,36,36,72,72,144};
  size_t oWc[6];
  for(int l=0;l<6;l++) oWc[l] = alloc((size_t)KTA[l]*(CoutA[l]>>4)*512*2);
  const size_t oSP = alloc((size_t)256*2*1536*4);
  const size_t oAB = alloc((size_t)2*1536*4);

  u16*   X    = (u16*)(ws + oX);
  u16*   Pb   = (u16*)(ws + oP);
  u16*   P2   = (u16*)(ws + oP2);
  float* Yf   = (float*)(ws + oYf);
  float* Qf   = (float*)(ws + oQf);
  u16*   AI   = (u16*)(ws + oQf);
  float* SP   = (float*)(ws + oSP);
  float* AB   = (float*)(ws + oAB);
  // FC buffers in oYf (dead after conv6 pool):
  u16*   F0   = (u16*)(ws + oYf);
  float* FA32 = (float*)(ws + oYf + (size_t)8*1024*1024);
  u16*   FAa  = (u16*)(ws + oYf + (size_t)10*1024*1024);
  float* FB32 = (float*)(ws + oYf + (size_t)12*1024*1024);
  u16*   FBa  = (u16*)(ws + oYf + (size_t)14*1024*1024);
  float* F3f  = (float*)(ws + oYf + (size_t)16*1024*1024);
  float* Pg   = (float*)(ws + oYf + (size_t)20*1024*1024);  // up to 25.2MB (fits in 67MB region)
  // FC weight fragments in oP (dead after conv6 conv):
  u16* Wf1 = (u16*)(ws + oP);
  u16* Wf2 = (u16*)(ws + oP + (size_t)26*1024*1024);
  u16* Wf3 = (u16*)(ws + oP + (size_t)31*1024*1024);

  for(int l=0;l<6;l++)
    k_prep_wfrag_conv<<<1024,256,0,stream>>>(cw[l], (u16*)(ws+oWc[l]), CoutA[l], CinA[l], KTA[l]);
  k_pad_input<<<2048,256,0,stream>>>(x, X);
  k_im2col<<<1024,256,0,stream>>>(X, AI);

  // ---- conv1: two 64-channel halves, fp32 pre-BN ----
  for(int h=0; h<2; h++){
    k_gemm_c1<<<4096,256,0,stream>>>(AI, (u16*)(ws+oWc[0]), cb[0], Yf, 32, 8, 64, h*64, h*64);
    k_stats_f32<<<256,256,8192,stream>>>(Yf, SP, 262144*64, 64, 256);
    k_bn_prep<<<1,256,0,stream>>>(SP, cgam[0]+h*64, cbt[0]+h*64, AB, 64, 256, 1.0f/262144.0f, h*64, 128);
    k_bn_act_f32<<<2048,256,0,stream>>>(Yf, AB+h*64, AB+128+h*64, Pb, 64, 262144, 32, 32, 128, h*64, 1, 1);
  }
  // ---- conv2: halves (128px x 64co tiles), pool, Pb -> P2 ----
  for(int h=0; h<2; h++){
    k_conv_mfma_t<4,2,128><<<dim3(2048,1),256,55488,stream>>>(Pb, (u16*)(ws+oWc[1]), cb[1], Yf, 32,32,128, 8, 4, h*64, h*64, 64);
    k_pool_f32<<<2048,256,0,stream>>>(Yf, Qf, 16, 16, 64);
    k_stats_f32<<<256,256,8192,stream>>>(Qf, SP, 65536*64, 64, 256);
    k_bn_prep<<<1,256,0,stream>>>(SP, cgam[1]+h*64, cbt[1]+h*64, AB, 64, 256, 1.0f/65536.0f, h*64, 128);
    k_bn_act_f32<<<2048,256,0,stream>>>(Qf, AB+h*64, AB+128+h*64, P2, 64, 65536, 16, 16, 128, h*64, 1, 1);
  }
  // ---- conv3: 64px x 128co, P2 -> Pb ----
  k_conv_mfma_t<2,4,128><<<dim3(1024,2),256,29376,stream>>>(P2, (u16*)(ws+oWc[2]), cb[2], Yf, 16,16,128, 16, 4, 0,0, 256);
  k_stats_f32<<<256,256,8192,stream>>>(Yf, SP, 65536*256, 256, 256);
  k_bn_prep<<<1,256,0,stream>>>(SP, cgam[2], cbt[2], AB, 256, 256, 1.0f/65536.0f, 0, 256);
  k_bn_act_f32<<<2048,256,0,stream>>>(Yf, AB, AB+256, Pb, 256, 65536, 16, 16, 256, 0, 1, 1);
  // ---- conv4: 64px x 128co, pool, Pb -> P2 ----
  k_conv_mfma_t<2,4,256><<<dim3(1024,2),256,57024,stream>>>(Pb, (u16*)(ws+oWc[3]), cb[3], Yf, 16,16,256, 16, 4, 0,0, 256);
  k_pool_f32<<<2048,256,0,stream>>>(Yf, Qf, 8, 8, 256);
  k_stats_f32<<<256,256,8192,stream>>>(Qf, SP, 16384*256, 256, 256);
  k_bn_prep<<<1,256,0,stream>>>(SP, cgam[3], cbt[3], AB, 256, 256, 1.0f/16384.0f, 0, 256);
  k_bn_act_f32<<<2048,256,0,stream>>>(Qf, AB, AB+256, P2, 256, 16384, 8, 8, 256, 0, 1, 1);
  // ---- conv5: 64px x 128co, P2 -> Pb ----
  k_conv_mfma_t<2,4,256><<<dim3(256,4),256,52800,stream>>>(P2, (u16*)(ws+oWc[4]), cb[4], Yf, 8,8,256, 32, 8, 0,0, 512);
  k_stats_f32<<<256,256,8192,stream>>>(Yf, SP, 16384*512, 512, 256);
  k_bn_prep<<<2,256,0,stream>>>(SP, cgam[4], cbt[4], AB, 512, 256, 1.0f/16384.0f, 0, 512);
  k_bn_act_f32<<<2048,256,0,stream>>>(Yf, AB, AB+512, Pb, 512, 16384, 8, 8, 512, 0, 1, 1);
  // ---- conv6: 64px x 128co, pool, Pb -> F0 (flat) ----
  k_conv_mfma_t<2,4,256><<<dim3(256,4),256,52800,stream>>>(Pb, (u16*)(ws+oWc[5]), cb[5], Yf, 8,8,512, 32, 8, 0,0, 512);
  k_pool_f32<<<2048,256,0,stream>>>(Yf, Qf, 4, 4, 512);
  k_stats_f32<<<256,256,8192,stream>>>(Qf, SP, 4096*512, 512, 256);
  k_bn_prep<<<2,256,0,stream>>>(SP, cgam[5], cbt[5], AB, 512, 256, 1.0f/4096.0f, 0, 512);
  k_bn_act_f32<<<512,256,0,stream>>>(Qf, AB, AB+512, F0, 512, 4096, 4, 4, 512, 0, 0, 1);

  // ---- FC weight fragments (oP is dead now) ----
  k_prep_wfrag_fc<<<2048,256,0,stream>>>(fw[0], Wf1, 1536, 8192, 96, 1);
  k_prep_wfrag_fc<<<1024,256,0,stream>>>(fw[1], Wf2, 1536, 1536, 96, 0);
  k_prep_wfrag_fc<<<64,256,0,stream>>>  (fw[2], Wf3, 10,   1536, 4,  0);

  // FC1 (split-K z=16)
  k_gemm_part<<<dim3(4,24,16),256,0,stream>>>(F0, Wf1, Pg, 256, 8192, 96, 1536, 16);
  k_fc_finish_f32<<<768,256,0,stream>>>(Pg, fbias[0], FA32, 256, 1536, 1536, 16);
  k_stats_f32<<<16,256,12288,stream>>>(FA32, SP, 256*1536, 1536, 16);
  k_bn_prep<<<6,256,0,stream>>>(SP, fg[0], fbt[0], AB, 1536, 16, 1.0f/256.0f, 0, 1536);
  k_bn_act_f32<<<256,256,0,stream>>>(FA32, AB, AB+1536, FAa, 1536, 256, 0,0, 1536, 0, 0, 1);
  // FC2 (split-K z=8)
  k_gemm_part<<<dim3(4,24,8),256,0,stream>>>(FAa, Wf2, Pg, 256, 1536, 96, 1536, 6);
  k_fc_finish_f32<<<768,256,0,stream>>>(Pg, fbias[1], FB32, 256, 1536, 1536, 8);
  k_stats_f32<<<16,256,12288,stream>>>(FB32, SP, 256*1536, 1536, 16);
  k_bn_prep<<<6,256,0,stream>>>(SP, fg[1], fbt[1], AB, 1536, 16, 1.0f/256.0f, 0, 1536);
  k_bn_act_f32<<<256,256,0,stream>>>(FB32, AB, AB+1536, FBa, 1536, 256, 0,0, 1536, 0, 0, 1);
  // FC3 (N padded to 64) -> BN (no clamp) -> f32 out
  k_gemm_part<<<dim3(4,1,4),256,0,stream>>>(FBa, Wf3, Pg, 256, 1536, 4, 64, 12);
  k_fc_finish_f32<<<16,256,0,stream>>>(Pg, fbias[2], F3f, 256, 10, 64, 4);
  k_stats_f32<<<4,256,256,stream>>>(F3f, SP, 2560, 10, 4);
  k_bn_prep<<<1,256,0,stream>>>(SP, fg[2], fbt[2], AB, 10, 4, 1.0f/256.0f, 0, 10);
  k_final<<<10,256,0,stream>>>(F3f, AB, (float*)d_out, 10, 2560);
}

// Round 5
// 1059.886 us; speedup vs baseline: 7.1038x; 1.7253x over previous
//
#include <hip/hip_runtime.h>
#include <stdint.h>

typedef unsigned short u16;
typedef unsigned int   u32;
typedef __attribute__((ext_vector_type(8))) short bf16x8;
typedef __attribute__((ext_vector_type(4))) float f32x4;

__device__ __forceinline__ float b2f(u16 u){ u32 i = ((u32)u) << 16; float f; __builtin_memcpy(&f,&i,4); return f; }
__device__ __forceinline__ u16 f2b(float f){ u32 i; __builtin_memcpy(&i,&f,4); i += 0x7FFFu + ((i>>16)&1u); return (u16)(i>>16); }

// ---------- weight prep: MFMA B-fragment layout ----------
__global__ void k_prep_wfrag_conv(const float* __restrict__ w, u16* __restrict__ wf,
                                  int Cout, int Cin, int KT){
  int NCT = Cout >> 4;
  int total = KT*NCT*512;
  int Kmax = 9*Cin;
  for(int i = blockIdx.x*256 + threadIdx.x; i < total; i += gridDim.x*256){
    int i8 = i & 7; int lane = (i>>3)&63; int t = i>>9;
    int ct = t % NCT; int kt = t / NCT;
    int k = kt*32 + ((lane>>4)<<3) + i8;
    int co = (ct<<4) + (lane&15);
    u16 v = 0;
    if(k < Kmax){
      int tap = k / Cin; int ci = k - tap*Cin;
      v = (w[(size_t)(co*Cin+ci)*9 + tap] >= 0.f) ? (u16)0x3F80 : (u16)0xBF80;
    }
    wf[i] = v;
  }
}
__global__ void k_prep_wfrag_fc(const float* __restrict__ w, u16* __restrict__ wf,
                                int Nf, int K, int NCTp, int permute){
  int total = (K>>5)*NCTp*512;
  for(int i = blockIdx.x*256 + threadIdx.x; i < total; i += gridDim.x*256){
    int i8 = i & 7; int lane = (i>>3)&63; int t = i>>9;
    int ct = t % NCTp; int kt = t / NCTp;
    int k = kt*32 + ((lane>>4)<<3) + i8;
    int n = (ct<<4) + (lane&15);
    u16 v = 0;
    if(n < Nf){
      int kr = permute ? ((k & 511)*16 + (k >> 9)) : k;
      v = (w[(size_t)n*K + kr] >= 0.f) ? (u16)0x3F80 : (u16)0xBF80;
    }
    wf[i] = v;
  }
}

// x (256,3,32,32) f32 NCHW -> (256,34,34,3) bf16 NHWC edge-padded
__global__ void k_pad_input(const float* __restrict__ x, u16* __restrict__ p){
  int total = 256*34*34*3;
  for(int i = blockIdx.x*256 + threadIdx.x; i < total; i += gridDim.x*256){
    int c = i % 3; int t = i / 3; int wp = t % 34; t /= 34; int hp = t % 34; int n = t / 34;
    int h = hp-1; h = h<0?0:(h>31?31:h);
    int w = wp-1; w = w<0?0:(w>31?31:w);
    p[i] = f2b(x[((size_t)(n*3+c)*32 + h)*32 + w]);
  }
}

// conv1 im2col: padded -> AI[262144][32], k=tap*3+ci, k>=27 zero
__global__ void k_im2col(const u16* __restrict__ xp, u16* __restrict__ AI){
  int m = blockIdx.x*256 + threadIdx.x;
  int w = m & 31; int h = (m>>5)&31; int n = m>>10;
  u16 buf[32];
  #pragma unroll
  for(int j=27;j<32;j++) buf[j]=0;
  #pragma unroll
  for(int tap=0;tap<9;tap++){
    int dh=tap/3, dw=tap-dh*3;
    const u16* s = xp + ((size_t)(n*34 + h+dh)*34 + (w+dw))*3;
    buf[tap*3+0]=s[0]; buf[tap*3+1]=s[1]; buf[tap*3+2]=s[2];
  }
  uint4* d = (uint4*)(AI + (size_t)m*32);
  const uint4* b4 = (const uint4*)buf;
  d[0]=b4[0]; d[1]=b4[1]; d[2]=b4[2]; d[3]=b4[3];
}

// ---------- conv: implicit GEMM MFMA, reg-pipelined, fused pool+stats ----------
// 4 waves (2Mx2N); tile BM=2*MF*16 px x BN=2*NF*16 couts; H=W (square)
template<int MF,int NF,int CS,int W,int POOL,int STATS>
__global__ __launch_bounds__(256) void k_conv_t(
    const u16* __restrict__ xp, const u16* __restrict__ wf, const float* __restrict__ bias,
    float* __restrict__ y, float* __restrict__ SP,
    int Cin, int NCT, int coutOff, int yOff, int yC)
{
  extern __shared__ u16 lds[];
  constexpr int BM = 2*MF*16;
  constexpr int R  = BM / W;
  constexpr int Wp = W + 2;
  constexpr int S  = CS + 8;
  constexpr int c32cnt = CS >> 5;
  constexpr int c32log = (CS==256)?3:((CS==128)?2:1);
  constexpr int csLog  = (CS==256)?8:((CS==128)?7:6);
  constexpr int wLog   = (W==32)?5:((W==16)?4:3);
  constexpr int hblocks = W / R;
  constexpr int NKt = 9*c32cnt;

  const int tid = threadIdx.x, lane = tid&63, wid = tid>>6;
  const int wm = wid&1, wn = wid>>1;
  const int n  = blockIdx.x / hblocks;
  const int h0 = (blockIdx.x % hblocks) * R;
  const int cb = coutOff + blockIdx.y*(2*NF*16);
  const int KTall = Cin >> 5;
  const int halves = Cin / CS;
  const int ctb = (cb>>4) + wn*NF;

  int offA[MF];
  #pragma unroll
  for(int fm=0; fm<MF; fm++){
    int p = (wm*MF+fm)*16 + (lane & 15);
    int rl = p >> wLog; int w_ = p & (W-1);
    offA[fm] = (rl*Wp + w_)*S + ((lane>>4)<<3);
  }

  f32x4 acc[MF][NF];
  #pragma unroll
  for(int i=0;i<MF;i++)
    #pragma unroll
    for(int j=0;j<NF;j++) acc[i][j] = (f32x4){0.f,0.f,0.f,0.f};

  constexpr int total8 = ((R+2)*Wp*CS) >> 3;

  for(int hv=0; hv<halves; hv++){
    __syncthreads();
    {
      const u16* gx = xp + ((size_t)(n*(W+2) + h0))*(size_t)(Wp*Cin) + (size_t)hv*CS;
      for(int i8=tid; i8<total8; i8+=256){
        int e = i8 << 3; int pix = e >> csLog; int ci = e & (CS-1);
        *(uint4*)(lds + pix*S + ci) = *(const uint4*)(gx + (size_t)pix*Cin + ci);
      }
    }
    __syncthreads();
    const int ktb = (hv*CS) >> 5;

    auto loadf = [&](int i, bf16x8 (&AF)[MF], bf16x8 (&BF)[NF]){
      int tap = i >> c32log; int c32 = i & (c32cnt-1);
      int dh = (tap*11) >> 5; int dw = tap - dh*3;
      int kt = tap*KTall + ktb + c32;
      const u16* bp = wf + (((size_t)kt*NCT + ctb)*64 + lane)*8;
      #pragma unroll
      for(int fn=0;fn<NF;fn++) BF[fn] = *(const bf16x8*)(bp + fn*512);
      const int toff = (dh*Wp + dw)*S + (c32<<5);
      #pragma unroll
      for(int fm=0;fm<MF;fm++) AF[fm] = *(const bf16x8*)(lds + offA[fm] + toff);
    };
    auto domf = [&](bf16x8 (&AF)[MF], bf16x8 (&BF)[NF]){
      #pragma unroll
      for(int fm=0;fm<MF;fm++)
        #pragma unroll
        for(int fn=0;fn<NF;fn++)
          acc[fm][fn] = __builtin_amdgcn_mfma_f32_16x16x32_bf16(AF[fm],BF[fn],acc[fm][fn],0,0,0);
    };

    bf16x8 Aa[MF], Ba[NF], Ab[MF], Bb2[NF];
    loadf(0, Aa, Ba);
    for(int i=0; i<NKt; i+=2){
      loadf(i+1, Ab, Bb2);
      domf(Aa, Ba);
      int nx = i+2; if(nx > NKt-1) nx = NKt-1;
      loadf(nx, Aa, Ba);
      domf(Ab, Bb2);
    }
  }

  // ---------- epilogue: bias, (pool), write, (stats) ----------
  const int col = lane & 15, g = lane >> 4, rowq = g << 2;
  const int pb = blockIdx.x;
  #pragma unroll
  for(int fn=0; fn<NF; fn++){
    const int coutG = cb + (wn*NF+fn)*16 + col;
    const float bs = bias[coutG];
    const int cl = coutG - yOff;
    float vals[MF][4];
    #pragma unroll
    for(int fm=0;fm<MF;fm++)
      #pragma unroll
      for(int ri=0;ri<4;ri++) vals[fm][ri] = acc[fm][fn][ri] + bs;

    float s = 0.f, q = 0.f;
    if constexpr (!POOL){
      #pragma unroll
      for(int fm=0;fm<MF;fm++){
        #pragma unroll
        for(int ri=0;ri<4;ri++){
          int p = (wm*MF+fm)*16 + rowq + ri;
          int rl = p >> wLog; int w_ = p & (W-1);
          y[(((size_t)n*W + h0+rl)*W + w_)*(size_t)yC + cl] = vals[fm][ri];
          if constexpr (STATS){ s += vals[fm][ri]; q += vals[fm][ri]*vals[fm][ri]; }
        }
      }
    } else {
      constexpr int HO = W/2;
      if constexpr (W==32){
        #pragma unroll
        for(int pp=0;pp<2;pp++){
          float pv[4];
          #pragma unroll
          for(int ri=0;ri<4;ri++) pv[ri] = fmaxf(vals[pp][ri], vals[pp+2][ri]);
          float po0 = fmaxf(pv[0],pv[1]), po1 = fmaxf(pv[2],pv[3]);
          int pr = (h0>>1) + wm;
          int wo = pp*8 + (rowq>>1);
          size_t base = (((size_t)n*HO + pr)*HO + wo)*(size_t)yC + cl;
          y[base] = po0; y[base + yC] = po1;
          if constexpr (STATS){ s += po0 + po1; q += po0*po0 + po1*po1; }
        }
      } else if constexpr (W==16){
        #pragma unroll
        for(int pp=0;pp<2;pp++){
          float pv[4];
          #pragma unroll
          for(int ri=0;ri<4;ri++) pv[ri] = fmaxf(vals[2*pp][ri], vals[2*pp+1][ri]);
          float po0 = fmaxf(pv[0],pv[1]), po1 = fmaxf(pv[2],pv[3]);
          int pr = (h0>>1) + wm*2 + pp;
          int wo = (rowq>>1);
          size_t base = (((size_t)n*HO + pr)*HO + wo)*(size_t)yC + cl;
          y[base] = po0; y[base + yC] = po1;
          if constexpr (STATS){ s += po0 + po1; q += po0*po0 + po1*po1; }
        }
      } else { // W==8, MF==2: vertical pair across lane^32
        #pragma unroll
        for(int fm=0;fm<2;fm++){
          float pv[4];
          #pragma unroll
          for(int ri=0;ri<4;ri++){
            float o = __shfl_xor(vals[fm][ri], 32);
            pv[ri] = fmaxf(vals[fm][ri], o);
          }
          if(g < 2){
            float po0 = fmaxf(pv[0],pv[1]), po1 = fmaxf(pv[2],pv[3]);
            int pr = wm*2 + fm;
            int wo = g*2;
            size_t base = (((size_t)n*HO + pr)*HO + wo)*(size_t)yC + cl;
            y[base] = po0; y[base + yC] = po1;
            if constexpr (STATS){ s += po0 + po1; q += po0*po0 + po1*po1; }
          }
        }
      }
    }
    if constexpr (STATS){
      s += __shfl_xor(s, 16); s += __shfl_xor(s, 32);
      q += __shfl_xor(q, 16); q += __shfl_xor(q, 32);
      if(lane < 16){
        atomicAdd(&SP[(size_t)pb*2*yC + cl], s);
        atomicAdd(&SP[(size_t)pb*2*yC + yC + cl], q);
      }
    }
  }
}

// ---------- conv1 GEMM over im2col (K=32), fp32 out, fused stats ----------
__global__ __launch_bounds__(256) void k_gemm_c1(
    const u16* __restrict__ A, const u16* __restrict__ wf, const float* __restrict__ bias,
    float* __restrict__ y, float* __restrict__ SP, int K, int NCT, int yC, int coutOff, int yOff)
{
  const int tid = threadIdx.x; const int lane = tid & 63; const int wid = tid >> 6;
  const int wm = wid & 1, wn = wid >> 1;
  const int mb = blockIdx.x*64;
  const int col = lane & 15;
  f32x4 acc[2][2];
  #pragma unroll
  for(int i=0;i<2;i++){ acc[i][0]=(f32x4){0.f,0.f,0.f,0.f}; acc[i][1]=(f32x4){0.f,0.f,0.f,0.f}; }
  const u16* a0p = A + (size_t)(mb + wm*32 + col)*K + ((lane>>4)<<3);
  const u16* a1p = a0p + (size_t)16*K;
  const int ct = (coutOff>>4) + wn*2;
  const int KT = K >> 5;
  for(int kt=0; kt<KT; kt++){
    bf16x8 a0 = *(const bf16x8*)(a0p + (size_t)kt*32);
    bf16x8 a1 = *(const bf16x8*)(a1p + (size_t)kt*32);
    const u16* bp = wf + (((size_t)kt*NCT + ct)*64 + lane)*8;
    bf16x8 b0 = *(const bf16x8*)(bp);
    bf16x8 b1 = *(const bf16x8*)(bp + 512);
    acc[0][0] = __builtin_amdgcn_mfma_f32_16x16x32_bf16(a0,b0,acc[0][0],0,0,0);
    acc[0][1] = __builtin_amdgcn_mfma_f32_16x16x32_bf16(a0,b1,acc[0][1],0,0,0);
    acc[1][0] = __builtin_amdgcn_mfma_f32_16x16x32_bf16(a1,b0,acc[1][0],0,0,0);
    acc[1][1] = __builtin_amdgcn_mfma_f32_16x16x32_bf16(a1,b1,acc[1][1],0,0,0);
  }
  const int rowq = (lane>>4)<<2;
  #pragma unroll
  for(int fn=0; fn<2; fn++){
    int coutG = wn*32 + fn*16 + col + coutOff;
    float bs = bias[coutG];
    int cl = coutG - yOff;
    float s=0.f, q=0.f;
    #pragma unroll
    for(int fm=0; fm<2; fm++){
      #pragma unroll
      for(int ri=0; ri<4; ri++){
        int m = mb + wm*32 + fm*16 + rowq + ri;
        float v = acc[fm][fn][ri] + bs;
        y[(size_t)m*yC + cl] = v;
        s += v; q += v*v;
      }
    }
    s += __shfl_xor(s, 16); s += __shfl_xor(s, 32);
    q += __shfl_xor(q, 16); q += __shfl_xor(q, 32);
    if(lane < 16){
      atomicAdd(&SP[(size_t)blockIdx.x*2*yC + cl], s);
      atomicAdd(&SP[(size_t)blockIdx.x*2*yC + yC + cl], q);
    }
  }
}

// ---------- FC GEMM, split-K, fp32 partials ----------
__global__ __launch_bounds__(256) void k_gemm_part(
    const u16* __restrict__ A, const u16* __restrict__ wf, float* __restrict__ P,
    int M, int K, int NCT, int ncp, int KTC)
{
  const int tid = threadIdx.x; const int lane = tid & 63; const int wid = tid >> 6;
  const int wm = wid & 1, wn = wid >> 1;
  const int mb = blockIdx.x*64, nb = blockIdx.y*64, kz = blockIdx.z;
  const int col = lane & 15;
  f32x4 acc[2][2];
  #pragma unroll
  for(int i=0;i<2;i++){ acc[i][0]=(f32x4){0.f,0.f,0.f,0.f}; acc[i][1]=(f32x4){0.f,0.f,0.f,0.f}; }
  const u16* a0p = A + (size_t)(mb + wm*32 + col)*K + ((lane>>4)<<3);
  const u16* a1p = a0p + (size_t)16*K;
  const int kt0 = kz*KTC;
  for(int t=0; t<KTC; t++){
    int kt = kt0 + t;
    bf16x8 a0 = *(const bf16x8*)(a0p + (size_t)kt*32);
    bf16x8 a1 = *(const bf16x8*)(a1p + (size_t)kt*32);
    const u16* bp = wf + (((size_t)kt*NCT + (nb>>4) + wn*2)*64 + lane)*8;
    bf16x8 b0 = *(const bf16x8*)(bp);
    bf16x8 b1 = *(const bf16x8*)(bp + 512);
    acc[0][0] = __builtin_amdgcn_mfma_f32_16x16x32_bf16(a0,b0,acc[0][0],0,0,0);
    acc[0][1] = __builtin_amdgcn_mfma_f32_16x16x32_bf16(a0,b1,acc[0][1],0,0,0);
    acc[1][0] = __builtin_amdgcn_mfma_f32_16x16x32_bf16(a1,b0,acc[1][0],0,0,0);
    acc[1][1] = __builtin_amdgcn_mfma_f32_16x16x32_bf16(a1,b1,acc[1][1],0,0,0);
  }
  const int rowq = (lane>>4)<<2;
  #pragma unroll
  for(int fm=0; fm<2; fm++){
    #pragma unroll
    for(int fn=0; fn<2; fn++){
      #pragma unroll
      for(int ri=0; ri<4; ri++){
        int m = mb + wm*32 + fm*16 + rowq + ri;
        int c = nb + wn*32 + fn*16 + col;
        P[((size_t)kz*M + m)*ncp + c] = acc[fm][fn][ri];
      }
    }
  }
}

// ---------- per-channel sum/sumsq partials, fp32 input (FC layers) ----------
__global__ __launch_bounds__(256) void k_stats_f32(const float* __restrict__ in, float* __restrict__ part,
                                                   int total, int C, int CH){
  extern __shared__ float ls[];
  const int tid = threadIdx.x; const int b = blockIdx.x;
  const int cpg4 = C >> 2;
  const bool pow2p = ((C & 3)==0) && (cpg4>0) && ((256 % cpg4)==0);
  if(pow2p){
    int total4 = total >> 2;
    int per = ((total4 + CH - 1)/CH + 255) & ~255;
    int s = b*per; int e = s+per; if(e>total4) e=total4;
    float sm[4]={0,0,0,0}, sq[4]={0,0,0,0};
    for(int i=s+tid; i<e; i+=256){
      float4 v = *(const float4*)(in + ((size_t)i<<2));
      sm[0]+=v.x; sq[0]+=v.x*v.x; sm[1]+=v.y; sq[1]+=v.y*v.y;
      sm[2]+=v.z; sq[2]+=v.z*v.z; sm[3]+=v.w; sq[3]+=v.w*v.w;
    }
    #pragma unroll
    for(int j=0;j<4;j++){ ls[tid*8+j]=sm[j]; ls[tid*8+4+j]=sq[j]; }
    __syncthreads();
    int G = 256/cpg4;
    for(int c=tid;c<C;c+=256){
      int c4=c>>2, j=c&3; float ssum=0.f, ssq=0.f;
      for(int g=0; g<G; g++){ int t = g*cpg4 + c4; ssum += ls[t*8+j]; ssq += ls[t*8+4+j]; }
      part[(size_t)b*2*C + c] = ssum; part[(size_t)b*2*C + C + c] = ssq;
    }
  } else if((C & 3)==0){
    for(int i=tid;i<2*C;i+=256) ls[i]=0.f;
    __syncthreads();
    int total4 = total >> 2;
    int per = (total4 + CH - 1)/CH;
    int s = b*per; int e = s+per; if(e>total4) e=total4;
    for(int i=s+tid;i<e;i+=256){
      float4 v = *(const float4*)(in + ((size_t)i<<2));
      int c0 = (i % cpg4)*4;
      atomicAdd(&ls[c0+0], v.x); atomicAdd(&ls[C+c0+0], v.x*v.x);
      atomicAdd(&ls[c0+1], v.y); atomicAdd(&ls[C+c0+1], v.y*v.y);
      atomicAdd(&ls[c0+2], v.z); atomicAdd(&ls[C+c0+2], v.z*v.z);
      atomicAdd(&ls[c0+3], v.w); atomicAdd(&ls[C+c0+3], v.w*v.w);
    }
    __syncthreads();
    for(int c=tid;c<2*C;c+=256) part[(size_t)b*2*C + c] = ls[c];
  } else {
    for(int i=tid;i<2*C;i+=256) ls[i]=0.f;
    __syncthreads();
    int per = (total + CH - 1)/CH;
    int s = b*per; int e = s+per; if(e>total) e=total;
    for(int i=s+tid;i<e;i+=256){
      float v = in[i]; int c = i % C;
      atomicAdd(&ls[c], v); atomicAdd(&ls[C+c], v*v);
    }
    __syncthreads();
    for(int c=tid;c<2*C;c+=256) part[(size_t)b*2*C + c] = ls[c];
  }
}

// reduce partial rows -> AB[cbase+c]=A, AB[Cfull+cbase+c]=B. One block per channel.
__global__ void k_bn_prep2(const float* __restrict__ part, const float* __restrict__ g,
                           const float* __restrict__ bt, float* __restrict__ AB,
                           int C, int rows, float invCnt, int cbase, int Cfull){
  __shared__ float ls[512];
  int c = blockIdx.x; int tid = threadIdx.x;
  float s=0.f, q=0.f;
  for(int r=tid; r<rows; r+=256){ s += part[(size_t)r*2*C + c]; q += part[(size_t)r*2*C + C + c]; }
  ls[tid]=s; ls[256+tid]=q; __syncthreads();
  for(int st=128; st>0; st>>=1){
    if(tid<st){ ls[tid]+=ls[tid+st]; ls[256+tid]+=ls[256+tid+st]; }
    __syncthreads();
  }
  if(tid==0){
    float m = ls[0]*invCnt; float v = ls[256]*invCnt - m*m;
    float A = g[c]*rsqrtf(v + 1e-5f);
    AB[cbase+c] = A; AB[Cfull+cbase+c] = bt[c] - m*A;
  }
}

// normalize(fp32 in) + hardtanh + bf16 write (padded-with-edge-replication or flat)
__global__ void k_bn_act_f32(const float* __restrict__ in, const float* __restrict__ Aa,
                             const float* __restrict__ Bb, u16* __restrict__ out,
                             int Cbuf, int rows, int HO, int WO, int Cfull, int cbase,
                             int padMode, int clampF){
  int cpg = Cbuf >> 3;
  int total = rows * cpg;
  for(int i = blockIdx.x*256 + threadIdx.x; i < total; i += gridDim.x*256){
    int c8 = i % cpg; int row = i / cpg; int c0 = c8*8;
    float4 v0 = *(const float4*)(in + (size_t)i*8);
    float4 v1 = *(const float4*)(in + (size_t)i*8 + 4);
    float4 A0 = *(const float4*)(Aa + c0);
    float4 A1 = *(const float4*)(Aa + c0 + 4);
    float4 B0 = *(const float4*)(Bb + c0);
    float4 B1 = *(const float4*)(Bb + c0 + 4);
    float f[8];
    f[0]=v0.x*A0.x+B0.x; f[1]=v0.y*A0.y+B0.y; f[2]=v0.z*A0.z+B0.z; f[3]=v0.w*A0.w+B0.w;
    f[4]=v1.x*A1.x+B1.x; f[5]=v1.y*A1.y+B1.y; f[6]=v1.z*A1.z+B1.z; f[7]=v1.w*A1.w+B1.w;
    if(clampF){
      #pragma unroll
      for(int j=0;j<8;j++) f[j] = fminf(fmaxf(f[j], -1.f), 1.f);
    }
    uint4 o;
    o.x = (u32)f2b(f[0]) | ((u32)f2b(f[1])<<16);
    o.y = (u32)f2b(f[2]) | ((u32)f2b(f[3])<<16);
    o.z = (u32)f2b(f[4]) | ((u32)f2b(f[5])<<16);
    o.w = (u32)f2b(f[6]) | ((u32)f2b(f[7])<<16);
    if(!padMode){
      *(uint4*)(out + (size_t)row*Cbuf + c0) = o;
    } else {
      int w = row % WO; int t = row / WO; int h = t % HO; int n = t / HO;
      int Wp2 = WO + 2;
      size_t base = (size_t)n*(HO+2)*Wp2;
      #define WRP(hp,wp) *(uint4*)(out + ((base + (size_t)(hp)*Wp2 + (wp))*(size_t)Cfull) + cbase + c0) = o
      WRP(h+1, w+1);
      if(h==0)            WRP(0,    w+1);
      if(h==HO-1)         WRP(HO+1, w+1);
      if(w==0)            WRP(h+1,  0);
      if(w==WO-1)         WRP(h+1,  WO+1);
      if(h==0    && w==0)    WRP(0,    0);
      if(h==0    && w==WO-1) WRP(0,    WO+1);
      if(h==HO-1 && w==0)    WRP(HO+1, 0);
      if(h==HO-1 && w==WO-1) WRP(HO+1, WO+1);
      #undef WRP
    }
  }
}

__global__ void k_fc_finish_f32(const float* __restrict__ P, const float* __restrict__ bias,
                                float* __restrict__ y, int M, int Nf, int ncp, int CH){
  int total = M*Nf;
  for(int i = blockIdx.x*256 + threadIdx.x; i < total; i += gridDim.x*256){
    int nf = i % Nf; int m = i / Nf;
    float s = bias[nf];
    for(int z=0; z<CH; z++) s += P[((size_t)z*M + m)*ncp + nf];
    y[i] = s;
  }
}

__global__ void k_final(const float* __restrict__ y, const float* __restrict__ AB,
                        float* __restrict__ out, int C, int total){
  for(int i = blockIdx.x*256 + threadIdx.x; i < total; i += gridDim.x*256){
    int c = i % C;
    out[i] = y[i]*AB[c] + AB[C+c];
  }
}

// ================= host =================
extern "C" void kernel_launch(void* const* d_in, const int* in_sizes, int n_in,
                              void* d_out, int out_size, void* d_ws, size_t ws_size,
                              hipStream_t stream) {
  (void)in_sizes; (void)n_in; (void)out_size; (void)ws_size;
  const float* x = (const float*)d_in[0];
  const float *cw[6], *cb[6], *cgam[6], *cbt[6];
  for(int i=0;i<6;i++){
    cw[i]  =(const float*)d_in[1+4*i];
    cb[i]  =(const float*)d_in[2+4*i];
    cgam[i]=(const float*)d_in[3+4*i];
    cbt[i] =(const float*)d_in[4+4*i];
  }
  const float *fw[3], *fbias[3], *fg[3], *fbt[3];
  for(int i=0;i<3;i++){
    fw[i]   =(const float*)d_in[25+4*i];
    fbias[i]=(const float*)d_in[26+4*i];
    fg[i]   =(const float*)d_in[27+4*i];
    fbt[i]  =(const float*)d_in[28+4*i];
  }

  char* ws = (char*)d_ws;
  size_t off = 0;
  auto alloc = [&](size_t bytes){ size_t o = off; off = (off + bytes + 255) & ~(size_t)255; return o; };
  const size_t oX  = alloc((size_t)256*34*34*3*2);
  const size_t oP  = alloc((size_t)256*34*34*128*2);      // padded acts A; later FC wfrags
  const size_t oP2 = alloc((size_t)256*18*18*128*2);      // padded acts B
  const size_t oYf = alloc((size_t)67108864);             // fp32 pre-BN; later FC bufs
  const size_t oQf = alloc((size_t)16777216);             // fp32 pooled; first holds AI bf16
  const int CinA[6]  = {3,128,128,256,256,512};
  const int CoutA[6] = {128,128,256,256,512,512};
  const int KTA[6]   = {1,36,36,72,72,144};
  size_t oWc[6];
  for(int l=0;l<6;l++) oWc[l] = alloc((size_t)KTA[l]*(CoutA[l]>>4)*512*2);
  const size_t oSP = alloc((size_t)4096*128*4);           // stats partial rows (2MB max use)
  const size_t oAB = alloc((size_t)2*1536*4);

  u16*   X    = (u16*)(ws + oX);
  u16*   Pb   = (u16*)(ws + oP);
  u16*   P2   = (u16*)(ws + oP2);
  float* Yf   = (float*)(ws + oYf);
  float* Qf   = (float*)(ws + oQf);
  u16*   AI   = (u16*)(ws + oQf);
  float* SP   = (float*)(ws + oSP);
  float* AB   = (float*)(ws + oAB);
  u16*   F0   = (u16*)(ws + oYf);
  float* FA32 = (float*)(ws + oYf + (size_t)8*1024*1024);
  u16*   FAa  = (u16*)(ws + oYf + (size_t)10*1024*1024);
  float* FB32 = (float*)(ws + oYf + (size_t)12*1024*1024);
  u16*   FBa  = (u16*)(ws + oYf + (size_t)14*1024*1024);
  float* F3f  = (float*)(ws + oYf + (size_t)16*1024*1024);
  float* Pg   = (float*)(ws + oYf + (size_t)20*1024*1024);
  u16* Wf1 = (u16*)(ws + oP);
  u16* Wf2 = (u16*)(ws + oP + (size_t)26*1024*1024);
  u16* Wf3 = (u16*)(ws + oP + (size_t)31*1024*1024);

  for(int l=0;l<6;l++)
    k_prep_wfrag_conv<<<1024,256,0,stream>>>(cw[l], (u16*)(ws+oWc[l]), CoutA[l], CinA[l], KTA[l]);
  k_pad_input<<<2048,256,0,stream>>>(x, X);
  k_im2col<<<1024,256,0,stream>>>(X, AI);

  // ---- conv1: two 64-channel halves (fused stats) ----
  for(int h=0; h<2; h++){
    hipMemsetAsync(SP, 0, (size_t)4096*128*4, stream);
    k_gemm_c1<<<4096,256,0,stream>>>(AI, (u16*)(ws+oWc[0]), cb[0], Yf, SP, 32, 8, 64, h*64, h*64);
    k_bn_prep2<<<64,256,0,stream>>>(SP, cgam[0]+h*64, cbt[0]+h*64, AB, 64, 4096, 1.0f/262144.0f, h*64, 128);
    k_bn_act_f32<<<2048,256,0,stream>>>(Yf, AB+h*64, AB+128+h*64, Pb, 64, 262144, 32, 32, 128, h*64, 1, 1);
  }
  // ---- conv2: halves, fused pool+stats, Pb -> Qf -> P2 ----
  for(int h=0; h<2; h++){
    hipMemsetAsync(SP, 0, (size_t)2048*128*4, stream);
    k_conv_t<4,2,64,32,1,1><<<dim3(2048,1),256,29376,stream>>>(Pb, (u16*)(ws+oWc[1]), cb[1], Qf, SP, 128, 8, h*64, h*64, 64);
    k_bn_prep2<<<64,256,0,stream>>>(SP, cgam[1]+h*64, cbt[1]+h*64, AB, 64, 2048, 1.0f/65536.0f, h*64, 128);
    k_bn_act_f32<<<2048,256,0,stream>>>(Qf, AB+h*64, AB+128+h*64, P2, 64, 65536, 16, 16, 128, h*64, 1, 1);
  }
  // ---- conv3: fused stats, P2 -> Yf -> Pb ----
  hipMemsetAsync(SP, 0, (size_t)512*512*4, stream);
  k_conv_t<4,4,128,16,0,1><<<dim3(512,2),256,48960,stream>>>(P2, (u16*)(ws+oWc[2]), cb[2], Yf, SP, 128, 16, 0, 0, 256);
  k_bn_prep2<<<256,256,0,stream>>>(SP, cgam[2], cbt[2], AB, 256, 512, 1.0f/65536.0f, 0, 256);
  k_bn_act_f32<<<2048,256,0,stream>>>(Yf, AB, AB+256, Pb, 256, 65536, 16, 16, 256, 0, 1, 1);
  // ---- conv4: fused pool+stats, Pb -> Qf -> P2 ----
  hipMemsetAsync(SP, 0, (size_t)512*512*4, stream);
  k_conv_t<4,4,128,16,1,1><<<dim3(512,2),256,48960,stream>>>(Pb, (u16*)(ws+oWc[3]), cb[3], Qf, SP, 256, 16, 0, 0, 256);
  k_bn_prep2<<<256,256,0,stream>>>(SP, cgam[3], cbt[3], AB, 256, 512, 1.0f/16384.0f, 0, 256);
  k_bn_act_f32<<<2048,256,0,stream>>>(Qf, AB, AB+256, P2, 256, 16384, 8, 8, 256, 0, 1, 1);
  // ---- conv5: fused stats, P2 -> Yf -> Pb ----
  hipMemsetAsync(SP, 0, (size_t)256*1024*4, stream);
  k_conv_t<2,8,128,8,0,1><<<dim3(256,2),256,27200,stream>>>(P2, (u16*)(ws+oWc[4]), cb[4], Yf, SP, 256, 32, 0, 0, 512);
  k_bn_prep2<<<512,256,0,stream>>>(SP, cgam[4], cbt[4], AB, 512, 256, 1.0f/16384.0f, 0, 512);
  k_bn_act_f32<<<2048,256,0,stream>>>(Yf, AB, AB+512, Pb, 512, 16384, 8, 8, 512, 0, 1, 1);
  // ---- conv6: fused pool+stats, Pb -> Qf -> F0 ----
  hipMemsetAsync(SP, 0, (size_t)256*1024*4, stream);
  k_conv_t<2,8,128,8,1,1><<<dim3(256,2),256,27200,stream>>>(Pb, (u16*)(ws+oWc[5]), cb[5], Qf, SP, 512, 32, 0, 0, 512);
  k_bn_prep2<<<512,256,0,stream>>>(SP, cgam[5], cbt[5], AB, 512, 256, 1.0f/4096.0f, 0, 512);
  k_bn_act_f32<<<512,256,0,stream>>>(Qf, AB, AB+512, F0, 512, 4096, 4, 4, 512, 0, 0, 1);

  // ---- FC weight fragments (oP is dead now) ----
  k_prep_wfrag_fc<<<2048,256,0,stream>>>(fw[0], Wf1, 1536, 8192, 96, 1);
  k_prep_wfrag_fc<<<1024,256,0,stream>>>(fw[1], Wf2, 1536, 1536, 96, 0);
  k_prep_wfrag_fc<<<64,256,0,stream>>>  (fw[2], Wf3, 10,   1536, 4,  0);

  // FC1 (split-K z=16)
  k_gemm_part<<<dim3(4,24,16),256,0,stream>>>(F0, Wf1, Pg, 256, 8192, 96, 1536, 16);
  k_fc_finish_f32<<<768,256,0,stream>>>(Pg, fbias[0], FA32, 256, 1536, 1536, 16);
  k_stats_f32<<<16,256,12288,stream>>>(FA32, SP, 256*1536, 1536, 16);
  k_bn_prep2<<<1536,256,0,stream>>>(SP, fg[0], fbt[0], AB, 1536, 16, 1.0f/256.0f, 0, 1536);
  k_bn_act_f32<<<256,256,0,stream>>>(FA32, AB, AB+1536, FAa, 1536, 256, 0,0, 1536, 0, 0, 1);
  // FC2 (split-K z=8)
  k_gemm_part<<<dim3(4,24,8),256,0,stream>>>(FAa, Wf2, Pg, 256, 1536, 96, 1536, 6);
  k_fc_finish_f32<<<768,256,0,stream>>>(Pg, fbias[1], FB32, 256, 1536, 1536, 8);
  k_stats_f32<<<16,256,12288,stream>>>(FB32, SP, 256*1536, 1536, 16);
  k_bn_prep2<<<1536,256,0,stream>>>(SP, fg[1], fbt[1], AB, 1536, 16, 1.0f/256.0f, 0, 1536);
  k_bn_act_f32<<<256,256,0,stream>>>(FB32, AB, AB+1536, FBa, 1536, 256, 0,0, 1536, 0, 0, 1);
  // FC3 (N padded to 64) -> BN (no clamp) -> f32 out
  k_gemm_part<<<dim3(4,1,4),256,0,stream>>>(FBa, Wf3, Pg, 256, 1536, 4, 64, 12);
  k_fc_finish_f32<<<16,256,0,stream>>>(Pg, fbias[2], F3f, 256, 10, 64, 4);
  k_stats_f32<<<4,256,256,stream>>>(F3f, SP, 2560, 10, 4);
  k_bn_prep2<<<10,256,0,stream>>>(SP, fg[2], fbt[2], AB, 10, 4, 1.0f/256.0f, 0, 10);
  k_final<<<10,256,0,stream>>>(F3f, AB, (float*)d_out, 10, 2560);
}

// Round 6
// 853.174 us; speedup vs baseline: 8.8250x; 1.2423x over previous
//
#include <hip/hip_runtime.h>
#include <stdint.h>

typedef unsigned short u16;
typedef unsigned int   u32;
typedef __attribute__((ext_vector_type(8))) short bf16x8;
typedef __attribute__((ext_vector_type(4))) float f32x4;

__device__ __forceinline__ float b2f(u16 u){ u32 i = ((u32)u) << 16; float f; __builtin_memcpy(&f,&i,4); return f; }
__device__ __forceinline__ u16 f2b(float f){ u32 i; __builtin_memcpy(&i,&f,4); i += 0x7FFFu + ((i>>16)&1u); return (u16)(i>>16); }

// ---------- weight prep: MFMA B-fragment layout ----------
__global__ void k_prep_wfrag_conv(const float* __restrict__ w, u16* __restrict__ wf,
                                  int Cout, int Cin, int KT){
  int NCT = Cout >> 4;
  int total = KT*NCT*512;
  int Kmax = 9*Cin;
  for(int i = blockIdx.x*256 + threadIdx.x; i < total; i += gridDim.x*256){
    int i8 = i & 7; int lane = (i>>3)&63; int t = i>>9;
    int ct = t % NCT; int kt = t / NCT;
    int k = kt*32 + ((lane>>4)<<3) + i8;
    int co = (ct<<4) + (lane&15);
    u16 v = 0;
    if(k < Kmax){
      int tap = k / Cin; int ci = k - tap*Cin;
      v = (w[(size_t)(co*Cin+ci)*9 + tap] >= 0.f) ? (u16)0x3F80 : (u16)0xBF80;
    }
    wf[i] = v;
  }
}
__global__ void k_prep_wfrag_fc(const float* __restrict__ w, u16* __restrict__ wf,
                                int Nf, int K, int NCTp, int permute){
  int total = (K>>5)*NCTp*512;
  for(int i = blockIdx.x*256 + threadIdx.x; i < total; i += gridDim.x*256){
    int i8 = i & 7; int lane = (i>>3)&63; int t = i>>9;
    int ct = t % NCTp; int kt = t / NCTp;
    int k = kt*32 + ((lane>>4)<<3) + i8;
    int n = (ct<<4) + (lane&15);
    u16 v = 0;
    if(n < Nf){
      int kr = permute ? ((k & 511)*16 + (k >> 9)) : k;
      v = (w[(size_t)n*K + kr] >= 0.f) ? (u16)0x3F80 : (u16)0xBF80;
    }
    wf[i] = v;
  }
}

// x (256,3,32,32) f32 NCHW -> (256,34,34,3) bf16 NHWC edge-padded
__global__ void k_pad_input(const float* __restrict__ x, u16* __restrict__ p){
  int total = 256*34*34*3;
  for(int i = blockIdx.x*256 + threadIdx.x; i < total; i += gridDim.x*256){
    int c = i % 3; int t = i / 3; int wp = t % 34; t /= 34; int hp = t % 34; int n = t / 34;
    int h = hp-1; h = h<0?0:(h>31?31:h);
    int w = wp-1; w = w<0?0:(w>31?31:w);
    p[i] = f2b(x[((size_t)(n*3+c)*32 + h)*32 + w]);
  }
}

// conv1 im2col: padded -> AI[262144][32], k=tap*3+ci, k>=27 zero
__global__ void k_im2col(const u16* __restrict__ xp, u16* __restrict__ AI){
  int m = blockIdx.x*256 + threadIdx.x;
  int w = m & 31; int h = (m>>5)&31; int n = m>>10;
  u16 buf[32];
  #pragma unroll
  for(int j=27;j<32;j++) buf[j]=0;
  #pragma unroll
  for(int tap=0;tap<9;tap++){
    int dh=tap/3, dw=tap-dh*3;
    const u16* s = xp + ((size_t)(n*34 + h+dh)*34 + (w+dw))*3;
    buf[tap*3+0]=s[0]; buf[tap*3+1]=s[1]; buf[tap*3+2]=s[2];
  }
  uint4* d = (uint4*)(AI + (size_t)m*32);
  const uint4* b4 = (const uint4*)buf;
  d[0]=b4[0]; d[1]=b4[1]; d[2]=b4[2]; d[3]=b4[3];
}

// ---------- conv: implicit GEMM MFMA, reg-pipelined, fused pool+stats (no atomics) ----------
template<int MF,int NF,int CS,int W,int POOL,int STATS>
__global__ __launch_bounds__(256) void k_conv_t(
    const u16* __restrict__ xp, const u16* __restrict__ wf, const float* __restrict__ bias,
    float* __restrict__ y, float* __restrict__ SP,
    int Cin, int NCT, int coutOff, int yOff, int yC)
{
  extern __shared__ u16 lds[];
  __shared__ float sbuf[STATS ? 4*NF*16 : 4];
  constexpr int BM = 2*MF*16;
  constexpr int R  = BM / W;
  constexpr int Wp = W + 2;
  constexpr int S  = CS + 8;
  constexpr int c32cnt = CS >> 5;
  constexpr int c32log = (CS==256)?3:((CS==128)?2:1);
  constexpr int csLog  = (CS==256)?8:((CS==128)?7:6);
  constexpr int wLog   = (W==32)?5:((W==16)?4:3);
  constexpr int hblocks = W / R;
  constexpr int NKt = 9*c32cnt;
  constexpr int BN = 2*NF*16;

  const int tid = threadIdx.x, lane = tid&63, wid = tid>>6;
  const int wm = wid&1, wn = wid>>1;
  const int n  = blockIdx.x / hblocks;
  const int h0 = (blockIdx.x % hblocks) * R;
  const int cb = coutOff + blockIdx.y*BN;
  const int KTall = Cin >> 5;
  const int halves = Cin / CS;
  const int ctb = (cb>>4) + wn*NF;

  int offA[MF];
  #pragma unroll
  for(int fm=0; fm<MF; fm++){
    int p = (wm*MF+fm)*16 + (lane & 15);
    int rl = p >> wLog; int w_ = p & (W-1);
    offA[fm] = (rl*Wp + w_)*S + ((lane>>4)<<3);
  }

  f32x4 acc[MF][NF];
  #pragma unroll
  for(int i=0;i<MF;i++)
    #pragma unroll
    for(int j=0;j<NF;j++) acc[i][j] = (f32x4){0.f,0.f,0.f,0.f};

  constexpr int total8 = ((R+2)*Wp*CS) >> 3;

  for(int hv=0; hv<halves; hv++){
    __syncthreads();
    {
      const u16* gx = xp + ((size_t)(n*(W+2) + h0))*(size_t)(Wp*Cin) + (size_t)hv*CS;
      for(int i8=tid; i8<total8; i8+=256){
        int e = i8 << 3; int pix = e >> csLog; int ci = e & (CS-1);
        *(uint4*)(lds + pix*S + ci) = *(const uint4*)(gx + (size_t)pix*Cin + ci);
      }
    }
    __syncthreads();
    const int ktb = (hv*CS) >> 5;

    auto loadf = [&](int i, bf16x8 (&AF)[MF], bf16x8 (&BF)[NF]){
      int tap = i >> c32log; int c32 = i & (c32cnt-1);
      int dh = (tap*11) >> 5; int dw = tap - dh*3;
      int kt = tap*KTall + ktb + c32;
      const u16* bp = wf + (((size_t)kt*NCT + ctb)*64 + lane)*8;
      #pragma unroll
      for(int fn=0;fn<NF;fn++) BF[fn] = *(const bf16x8*)(bp + fn*512);
      const int toff = (dh*Wp + dw)*S + (c32<<5);
      #pragma unroll
      for(int fm=0;fm<MF;fm++) AF[fm] = *(const bf16x8*)(lds + offA[fm] + toff);
    };
    auto domf = [&](bf16x8 (&AF)[MF], bf16x8 (&BF)[NF]){
      #pragma unroll
      for(int fm=0;fm<MF;fm++)
        #pragma unroll
        for(int fn=0;fn<NF;fn++)
          acc[fm][fn] = __builtin_amdgcn_mfma_f32_16x16x32_bf16(AF[fm],BF[fn],acc[fm][fn],0,0,0);
    };

    bf16x8 Aa[MF], Ba[NF], Ab[MF], Bb2[NF];
    loadf(0, Aa, Ba);
    for(int i=0; i<NKt; i+=2){
      loadf(i+1, Ab, Bb2);
      domf(Aa, Ba);
      int nx = i+2; if(nx > NKt-1) nx = NKt-1;
      loadf(nx, Aa, Ba);
      domf(Ab, Bb2);
    }
  }

  // ---------- epilogue: bias, (pool), write, (stats) ----------
  const int col = lane & 15, g = lane >> 4, rowq = g << 2;
  float sarr[NF], qarr[NF];
  #pragma unroll
  for(int fn=0; fn<NF; fn++){
    const int coutG = cb + (wn*NF+fn)*16 + col;
    const float bs = bias[coutG];
    const int cl = coutG - yOff;
    float vals[MF][4];
    #pragma unroll
    for(int fm=0;fm<MF;fm++)
      #pragma unroll
      for(int ri=0;ri<4;ri++) vals[fm][ri] = acc[fm][fn][ri] + bs;

    float s = 0.f, q = 0.f;
    if constexpr (!POOL){
      #pragma unroll
      for(int fm=0;fm<MF;fm++){
        #pragma unroll
        for(int ri=0;ri<4;ri++){
          int p = (wm*MF+fm)*16 + rowq + ri;
          int rl = p >> wLog; int w_ = p & (W-1);
          y[(((size_t)n*W + h0+rl)*W + w_)*(size_t)yC + cl] = vals[fm][ri];
          if constexpr (STATS){ s += vals[fm][ri]; q += vals[fm][ri]*vals[fm][ri]; }
        }
      }
    } else {
      constexpr int HO = W/2;
      if constexpr (W==32){
        #pragma unroll
        for(int pp=0;pp<2;pp++){
          float pv[4];
          #pragma unroll
          for(int ri=0;ri<4;ri++) pv[ri] = fmaxf(vals[pp][ri], vals[pp+2][ri]);
          float po0 = fmaxf(pv[0],pv[1]), po1 = fmaxf(pv[2],pv[3]);
          int pr = (h0>>1) + wm;
          int wo = pp*8 + (rowq>>1);
          size_t base = (((size_t)n*HO + pr)*HO + wo)*(size_t)yC + cl;
          y[base] = po0; y[base + yC] = po1;
          if constexpr (STATS){ s += po0 + po1; q += po0*po0 + po1*po1; }
        }
      } else if constexpr (W==16){
        #pragma unroll
        for(int pp=0;pp<2;pp++){
          float pv[4];
          #pragma unroll
          for(int ri=0;ri<4;ri++) pv[ri] = fmaxf(vals[2*pp][ri], vals[2*pp+1][ri]);
          float po0 = fmaxf(pv[0],pv[1]), po1 = fmaxf(pv[2],pv[3]);
          int pr = (h0>>1) + wm*2 + pp;
          int wo = (rowq>>1);
          size_t base = (((size_t)n*HO + pr)*HO + wo)*(size_t)yC + cl;
          y[base] = po0; y[base + yC] = po1;
          if constexpr (STATS){ s += po0 + po1; q += po0*po0 + po1*po1; }
        }
      } else { // W==8, MF==2: vertical pair across lane^32
        #pragma unroll
        for(int fm=0;fm<2;fm++){
          float pv[4];
          #pragma unroll
          for(int ri=0;ri<4;ri++){
            float o = __shfl_xor(vals[fm][ri], 32);
            pv[ri] = fmaxf(vals[fm][ri], o);
          }
          if(g < 2){
            float po0 = fmaxf(pv[0],pv[1]), po1 = fmaxf(pv[2],pv[3]);
            int pr = wm*2 + fm;
            int wo = g*2;
            size_t base = (((size_t)n*HO + pr)*HO + wo)*(size_t)yC + cl;
            y[base] = po0; y[base + yC] = po1;
            if constexpr (STATS){ s += po0 + po1; q += po0*po0 + po1*po1; }
          }
        }
      }
    }
    if constexpr (STATS){
      s += __shfl_xor(s, 16); s += __shfl_xor(s, 32);
      q += __shfl_xor(q, 16); q += __shfl_xor(q, 32);
      sarr[fn] = s; qarr[fn] = q;
    }
  }
  if constexpr (STATS){
    if(wm==1 && lane<16){
      #pragma unroll
      for(int fn=0;fn<NF;fn++){
        int lc = (wn*NF+fn)*16 + col;
        sbuf[lc] = sarr[fn]; sbuf[BN+lc] = qarr[fn];
      }
    }
    __syncthreads();
    if(wm==0 && lane<16){
      #pragma unroll
      for(int fn=0;fn<NF;fn++){
        int lc = (wn*NF+fn)*16 + col;
        int cl = cb + (wn*NF+fn)*16 + col - yOff;
        SP[(size_t)blockIdx.x*2*yC + cl]      = sarr[fn] + sbuf[lc];
        SP[(size_t)blockIdx.x*2*yC + yC + cl] = qarr[fn] + sbuf[BN+lc];
      }
    }
  }
}

// ---------- conv1 GEMM over im2col (K=32), fp32 out, fused stats (no atomics) ----------
__global__ __launch_bounds__(256) void k_gemm_c1(
    const u16* __restrict__ A, const u16* __restrict__ wf, const float* __restrict__ bias,
    float* __restrict__ y, float* __restrict__ SP, int K, int NCT, int yC, int coutOff, int yOff)
{
  __shared__ float sb[128];
  const int tid = threadIdx.x; const int lane = tid & 63; const int wid = tid >> 6;
  const int wm = wid & 1, wn = wid >> 1;
  const int mb = blockIdx.x*64;
  const int col = lane & 15;
  f32x4 acc[2][2];
  #pragma unroll
  for(int i=0;i<2;i++){ acc[i][0]=(f32x4){0.f,0.f,0.f,0.f}; acc[i][1]=(f32x4){0.f,0.f,0.f,0.f}; }
  const u16* a0p = A + (size_t)(mb + wm*32 + col)*K + ((lane>>4)<<3);
  const u16* a1p = a0p + (size_t)16*K;
  const int ct = (coutOff>>4) + wn*2;
  const int KT = K >> 5;
  for(int kt=0; kt<KT; kt++){
    bf16x8 a0 = *(const bf16x8*)(a0p + (size_t)kt*32);
    bf16x8 a1 = *(const bf16x8*)(a1p + (size_t)kt*32);
    const u16* bp = wf + (((size_t)kt*NCT + ct)*64 + lane)*8;
    bf16x8 b0 = *(const bf16x8*)(bp);
    bf16x8 b1 = *(const bf16x8*)(bp + 512);
    acc[0][0] = __builtin_amdgcn_mfma_f32_16x16x32_bf16(a0,b0,acc[0][0],0,0,0);
    acc[0][1] = __builtin_amdgcn_mfma_f32_16x16x32_bf16(a0,b1,acc[0][1],0,0,0);
    acc[1][0] = __builtin_amdgcn_mfma_f32_16x16x32_bf16(a1,b0,acc[1][0],0,0,0);
    acc[1][1] = __builtin_amdgcn_mfma_f32_16x16x32_bf16(a1,b1,acc[1][1],0,0,0);
  }
  const int rowq = (lane>>4)<<2;
  float sarr[2], qarr[2];
  #pragma unroll
  for(int fn=0; fn<2; fn++){
    int coutG = wn*32 + fn*16 + col + coutOff;
    float bs = bias[coutG];
    int cl = coutG - yOff;
    float s=0.f, q=0.f;
    #pragma unroll
    for(int fm=0; fm<2; fm++){
      #pragma unroll
      for(int ri=0; ri<4; ri++){
        int m = mb + wm*32 + fm*16 + rowq + ri;
        float v = acc[fm][fn][ri] + bs;
        y[(size_t)m*yC + cl] = v;
        s += v; q += v*v;
      }
    }
    s += __shfl_xor(s, 16); s += __shfl_xor(s, 32);
    q += __shfl_xor(q, 16); q += __shfl_xor(q, 32);
    sarr[fn]=s; qarr[fn]=q;
  }
  if(wm==1 && lane<16){
    #pragma unroll
    for(int fn=0;fn<2;fn++){ int lc = wn*32+fn*16+col; sb[lc]=sarr[fn]; sb[64+lc]=qarr[fn]; }
  }
  __syncthreads();
  if(wm==0 && lane<16){
    #pragma unroll
    for(int fn=0;fn<2;fn++){
      int lc = wn*32+fn*16+col;
      SP[(size_t)blockIdx.x*2*yC + lc]      = sarr[fn] + sb[lc];
      SP[(size_t)blockIdx.x*2*yC + yC + lc] = qarr[fn] + sb[64+lc];
    }
  }
}

// ---------- FC GEMM, split-K, fp32 partials (TRANSPOSED: P[(kz*ncp+c)*M+m]) ----------
__global__ __launch_bounds__(256) void k_gemm_part(
    const u16* __restrict__ A, const u16* __restrict__ wf, float* __restrict__ P,
    int M, int K, int NCT, int ncp, int KTC)
{
  const int tid = threadIdx.x; const int lane = tid & 63; const int wid = tid >> 6;
  const int wm = wid & 1, wn = wid >> 1;
  const int mb = blockIdx.x*64, nb = blockIdx.y*64, kz = blockIdx.z;
  const int col = lane & 15;
  f32x4 acc[2][2];
  #pragma unroll
  for(int i=0;i<2;i++){ acc[i][0]=(f32x4){0.f,0.f,0.f,0.f}; acc[i][1]=(f32x4){0.f,0.f,0.f,0.f}; }
  const u16* a0p = A + (size_t)(mb + wm*32 + col)*K + ((lane>>4)<<3);
  const u16* a1p = a0p + (size_t)16*K;
  const int kt0 = kz*KTC;
  for(int t=0; t<KTC; t++){
    int kt = kt0 + t;
    bf16x8 a0 = *(const bf16x8*)(a0p + (size_t)kt*32);
    bf16x8 a1 = *(const bf16x8*)(a1p + (size_t)kt*32);
    const u16* bp = wf + (((size_t)kt*NCT + (nb>>4) + wn*2)*64 + lane)*8;
    bf16x8 b0 = *(const bf16x8*)(bp);
    bf16x8 b1 = *(const bf16x8*)(bp + 512);
    acc[0][0] = __builtin_amdgcn_mfma_f32_16x16x32_bf16(a0,b0,acc[0][0],0,0,0);
    acc[0][1] = __builtin_amdgcn_mfma_f32_16x16x32_bf16(a0,b1,acc[0][1],0,0,0);
    acc[1][0] = __builtin_amdgcn_mfma_f32_16x16x32_bf16(a1,b0,acc[1][0],0,0,0);
    acc[1][1] = __builtin_amdgcn_mfma_f32_16x16x32_bf16(a1,b1,acc[1][1],0,0,0);
  }
  const int rowq = (lane>>4)<<2;
  #pragma unroll
  for(int fm=0; fm<2; fm++){
    #pragma unroll
    for(int fn=0; fn<2; fn++){
      int mbase = mb + wm*32 + fm*16 + rowq;
      int c = nb + wn*32 + fn*16 + col;
      *(f32x4*)(P + ((size_t)kz*ncp + c)*M + mbase) = acc[fm][fn];
    }
  }
}

// ---------- fused FC finish: sum partials + bias -> batch-BN -> act -> write ----------
__global__ __launch_bounds__(256) void k_fc_fuse(
    const float* __restrict__ P, const float* __restrict__ bias,
    const float* __restrict__ g, const float* __restrict__ bt,
    u16* __restrict__ outb, float* __restrict__ outf,
    int Nf, int ncp, int CH, int clampF)
{
  __shared__ float sb[10];
  const int nf = blockIdx.x; const int m = threadIdx.x;   // M == 256
  float v = bias[nf];
  for(int z=0; z<CH; z++) v += P[((size_t)z*ncp + nf)*256 + m];
  float s = v, q = v*v;
  #pragma unroll
  for(int d=1; d<64; d<<=1){ s += __shfl_xor(s,d); q += __shfl_xor(q,d); }
  if((m&63)==0){ sb[m>>6]=s; sb[4+(m>>6)]=q; }
  __syncthreads();
  if(m==0){
    float st=sb[0]+sb[1]+sb[2]+sb[3], qt=sb[4]+sb[5]+sb[6]+sb[7];
    float mean=st*(1.f/256.f); float var=qt*(1.f/256.f)-mean*mean;
    float A=g[nf]*rsqrtf(var+1e-5f);
    sb[8]=A; sb[9]=bt[nf]-mean*A;
  }
  __syncthreads();
  float o = v*sb[8]+sb[9];
  if(clampF) o = fminf(fmaxf(o,-1.f),1.f);
  if(outb) outb[(size_t)m*Nf+nf] = f2b(o);
  else     outf[(size_t)m*Nf+nf] = o;
}

// reduce partial rows -> AB[cbase+c]=A, AB[Cfull+cbase+c]=B. One block per channel.
__global__ void k_bn_prep2(const float* __restrict__ part, const float* __restrict__ g,
                           const float* __restrict__ bt, float* __restrict__ AB,
                           int C, int rows, float invCnt, int cbase, int Cfull){
  __shared__ float ls[512];
  int c = blockIdx.x; int tid = threadIdx.x;
  float s=0.f, q=0.f;
  for(int r=tid; r<rows; r+=256){ s += part[(size_t)r*2*C + c]; q += part[(size_t)r*2*C + C + c]; }
  ls[tid]=s; ls[256+tid]=q; __syncthreads();
  for(int st=128; st>0; st>>=1){
    if(tid<st){ ls[tid]+=ls[tid+st]; ls[256+tid]+=ls[256+tid+st]; }
    __syncthreads();
  }
  if(tid==0){
    float m = ls[0]*invCnt; float v = ls[256]*invCnt - m*m;
    float A = g[c]*rsqrtf(v + 1e-5f);
    AB[cbase+c] = A; AB[Cfull+cbase+c] = bt[c] - m*A;
  }
}

// normalize(fp32 in) + hardtanh + bf16 write (padded-with-edge-replication or flat)
__global__ void k_bn_act_f32(const float* __restrict__ in, const float* __restrict__ Aa,
                             const float* __restrict__ Bb, u16* __restrict__ out,
                             int Cbuf, int rows, int HO, int WO, int Cfull, int cbase,
                             int padMode, int clampF){
  int cpg = Cbuf >> 3;
  int total = rows * cpg;
  for(int i = blockIdx.x*256 + threadIdx.x; i < total; i += gridDim.x*256){
    int c8 = i % cpg; int row = i / cpg; int c0 = c8*8;
    float4 v0 = *(const float4*)(in + (size_t)i*8);
    float4 v1 = *(const float4*)(in + (size_t)i*8 + 4);
    float4 A0 = *(const float4*)(Aa + c0);
    float4 A1 = *(const float4*)(Aa + c0 + 4);
    float4 B0 = *(const float4*)(Bb + c0);
    float4 B1 = *(const float4*)(Bb + c0 + 4);
    float f[8];
    f[0]=v0.x*A0.x+B0.x; f[1]=v0.y*A0.y+B0.y; f[2]=v0.z*A0.z+B0.z; f[3]=v0.w*A0.w+B0.w;
    f[4]=v1.x*A1.x+B1.x; f[5]=v1.y*A1.y+B1.y; f[6]=v1.z*A1.z+B1.z; f[7]=v1.w*A1.w+B1.w;
    if(clampF){
      #pragma unroll
      for(int j=0;j<8;j++) f[j] = fminf(fmaxf(f[j], -1.f), 1.f);
    }
    uint4 o;
    o.x = (u32)f2b(f[0]) | ((u32)f2b(f[1])<<16);
    o.y = (u32)f2b(f[2]) | ((u32)f2b(f[3])<<16);
    o.z = (u32)f2b(f[4]) | ((u32)f2b(f[5])<<16);
    o.w = (u32)f2b(f[6]) | ((u32)f2b(f[7])<<16);
    if(!padMode){
      *(uint4*)(out + (size_t)row*Cbuf + c0) = o;
    } else {
      int w = row % WO; int t = row / WO; int h = t % HO; int n = t / HO;
      int Wp2 = WO + 2;
      size_t base = (size_t)n*(HO+2)*Wp2;
      #define WRP(hp,wp) *(uint4*)(out + ((base + (size_t)(hp)*Wp2 + (wp))*(size_t)Cfull) + cbase + c0) = o
      WRP(h+1, w+1);
      if(h==0)            WRP(0,    w+1);
      if(h==HO-1)         WRP(HO+1, w+1);
      if(w==0)            WRP(h+1,  0);
      if(w==WO-1)         WRP(h+1,  WO+1);
      if(h==0    && w==0)    WRP(0,    0);
      if(h==0    && w==WO-1) WRP(0,    WO+1);
      if(h==HO-1 && w==0)    WRP(HO+1, 0);
      if(h==HO-1 && w==WO-1) WRP(HO+1, WO+1);
      #undef WRP
    }
  }
}

// ================= host =================
extern "C" void kernel_launch(void* const* d_in, const int* in_sizes, int n_in,
                              void* d_out, int out_size, void* d_ws, size_t ws_size,
                              hipStream_t stream) {
  (void)in_sizes; (void)n_in; (void)out_size; (void)ws_size;
  const float* x = (const float*)d_in[0];
  const float *cw[6], *cb[6], *cgam[6], *cbt[6];
  for(int i=0;i<6;i++){
    cw[i]  =(const float*)d_in[1+4*i];
    cb[i]  =(const float*)d_in[2+4*i];
    cgam[i]=(const float*)d_in[3+4*i];
    cbt[i] =(const float*)d_in[4+4*i];
  }
  const float *fw[3], *fbias[3], *fg[3], *fbt[3];
  for(int i=0;i<3;i++){
    fw[i]   =(const float*)d_in[25+4*i];
    fbias[i]=(const float*)d_in[26+4*i];
    fg[i]   =(const float*)d_in[27+4*i];
    fbt[i]  =(const float*)d_in[28+4*i];
  }

  char* ws = (char*)d_ws;
  size_t off = 0;
  auto alloc = [&](size_t bytes){ size_t o = off; off = (off + bytes + 255) & ~(size_t)255; return o; };
  const size_t oX  = alloc((size_t)256*34*34*3*2);
  const size_t oP  = alloc((size_t)256*34*34*128*2);      // padded acts A; later FC wfrags
  const size_t oP2 = alloc((size_t)256*18*18*128*2);      // padded acts B
  const size_t oYf = alloc((size_t)67108864);             // fp32 pre-BN / pooled out; later FC bufs
  const size_t oQf = alloc((size_t)16777216);             // AI im2col; later F0
  const int CinA[6]  = {3,128,128,256,256,512};
  const int CoutA[6] = {128,128,256,256,512,512};
  const int KTA[6]   = {1,36,36,72,72,144};
  size_t oWc[6];
  for(int l=0;l<6;l++) oWc[l] = alloc((size_t)KTA[l]*(CoutA[l]>>4)*512*2);
  const size_t oSP = alloc((size_t)4096*128*4);           // stats partial rows (2MB)
  const size_t oAB = alloc((size_t)2*1536*4);

  u16*   X    = (u16*)(ws + oX);
  u16*   Pb   = (u16*)(ws + oP);
  u16*   P2   = (u16*)(ws + oP2);
  float* Yf   = (float*)(ws + oYf);
  u16*   AI   = (u16*)(ws + oQf);
  u16*   F0   = (u16*)(ws + oQf);       // bf16 256x8192 (4.2MB), written after AI is dead
  float* SP   = (float*)(ws + oSP);
  float* AB   = (float*)(ws + oAB);
  float* Pg   = (float*)(ws + oYf + (size_t)32*1024*1024); // split-K partials (25.2MB max)
  u16*   FAa  = (u16*)(ws + oYf + (size_t)58*1024*1024);
  u16*   FBa  = (u16*)(ws + oYf + (size_t)60*1024*1024);
  u16* Wf1 = (u16*)(ws + oP);
  u16* Wf2 = (u16*)(ws + oP + (size_t)26*1024*1024);
  u16* Wf3 = (u16*)(ws + oP + (size_t)31*1024*1024);

  for(int l=0;l<6;l++)
    k_prep_wfrag_conv<<<1024,256,0,stream>>>(cw[l], (u16*)(ws+oWc[l]), CoutA[l], CinA[l], KTA[l]);
  k_pad_input<<<2048,256,0,stream>>>(x, X);
  k_im2col<<<1024,256,0,stream>>>(X, AI);

  // ---- conv1: two 64-channel halves (fp32 Y in Yf, fused stats) ----
  for(int h=0; h<2; h++){
    k_gemm_c1<<<4096,256,0,stream>>>(AI, (u16*)(ws+oWc[0]), cb[0], Yf, SP, 32, 8, 64, h*64, h*64);
    k_bn_prep2<<<64,256,0,stream>>>(SP, cgam[0]+h*64, cbt[0]+h*64, AB, 64, 4096, 1.0f/262144.0f, h*64, 128);
    k_bn_act_f32<<<2048,256,0,stream>>>(Yf, AB+h*64, AB+128+h*64, Pb, 64, 262144, 32, 32, 128, h*64, 1, 1);
  }
  // ---- conv2: single pass, fused pool+stats, Pb -> Yf(pooled fp32) -> P2 ----
  k_conv_t<4,2,64,32,1,1><<<dim3(2048,2),256,29376,stream>>>(Pb, (u16*)(ws+oWc[1]), cb[1], Yf, SP, 128, 8, 0, 0, 128);
  k_bn_prep2<<<128,256,0,stream>>>(SP, cgam[1], cbt[1], AB, 128, 2048, 1.0f/65536.0f, 0, 128);
  k_bn_act_f32<<<2048,256,0,stream>>>(Yf, AB, AB+128, P2, 128, 65536, 16, 16, 128, 0, 1, 1);
  // ---- conv3: fused stats, P2 -> Yf -> Pb ----
  k_conv_t<4,4,128,16,0,1><<<dim3(512,2),256,48960,stream>>>(P2, (u16*)(ws+oWc[2]), cb[2], Yf, SP, 128, 16, 0, 0, 256);
  k_bn_prep2<<<256,256,0,stream>>>(SP, cgam[2], cbt[2], AB, 256, 512, 1.0f/65536.0f, 0, 256);
  k_bn_act_f32<<<2048,256,0,stream>>>(Yf, AB, AB+256, Pb, 256, 65536, 16, 16, 256, 0, 1, 1);
  // ---- conv4: fused pool+stats, Pb -> Yf(pooled) -> P2 ----
  k_conv_t<4,4,128,16,1,1><<<dim3(512,2),256,48960,stream>>>(Pb, (u16*)(ws+oWc[3]), cb[3], Yf, SP, 256, 16, 0, 0, 256);
  k_bn_prep2<<<256,256,0,stream>>>(SP, cgam[3], cbt[3], AB, 256, 512, 1.0f/16384.0f, 0, 256);
  k_bn_act_f32<<<2048,256,0,stream>>>(Yf, AB, AB+256, P2, 256, 16384, 8, 8, 256, 0, 1, 1);
  // ---- conv5: fused stats, P2 -> Yf -> Pb ----
  k_conv_t<2,4,128,8,0,1><<<dim3(256,4),256,27200,stream>>>(P2, (u16*)(ws+oWc[4]), cb[4], Yf, SP, 256, 32, 0, 0, 512);
  k_bn_prep2<<<512,256,0,stream>>>(SP, cgam[4], cbt[4], AB, 512, 256, 1.0f/16384.0f, 0, 512);
  k_bn_act_f32<<<2048,256,0,stream>>>(Yf, AB, AB+512, Pb, 512, 16384, 8, 8, 512, 0, 1, 1);
  // ---- conv6: fused pool+stats, Pb -> Yf(pooled) -> F0 ----
  k_conv_t<2,4,128,8,1,1><<<dim3(256,4),256,27200,stream>>>(Pb, (u16*)(ws+oWc[5]), cb[5], Yf, SP, 512, 32, 0, 0, 512);
  k_bn_prep2<<<512,256,0,stream>>>(SP, cgam[5], cbt[5], AB, 512, 256, 1.0f/4096.0f, 0, 512);
  k_bn_act_f32<<<512,256,0,stream>>>(Yf, AB, AB+512, F0, 512, 4096, 4, 4, 512, 0, 0, 1);

  // ---- FC weight fragments (oP is dead now) ----
  k_prep_wfrag_fc<<<2048,256,0,stream>>>(fw[0], Wf1, 1536, 8192, 96, 1);
  k_prep_wfrag_fc<<<1024,256,0,stream>>>(fw[1], Wf2, 1536, 1536, 96, 0);
  k_prep_wfrag_fc<<<64,256,0,stream>>>  (fw[2], Wf3, 10,   1536, 4,  0);

  // FC1
  k_gemm_part<<<dim3(4,24,16),256,0,stream>>>(F0, Wf1, Pg, 256, 8192, 96, 1536, 16);
  k_fc_fuse<<<1536,256,0,stream>>>(Pg, fbias[0], fg[0], fbt[0], FAa, nullptr, 1536, 1536, 16, 1);
  // FC2
  k_gemm_part<<<dim3(4,24,8),256,0,stream>>>(FAa, Wf2, Pg, 256, 1536, 96, 1536, 6);
  k_fc_fuse<<<1536,256,0,stream>>>(Pg, fbias[1], fg[1], fbt[1], FBa, nullptr, 1536, 1536, 8, 1);
  // FC3 (N padded to 64) -> BN (no clamp) -> f32 out
  k_gemm_part<<<dim3(4,1,4),256,0,stream>>>(FBa, Wf3, Pg, 256, 1536, 4, 64, 12);
  k_fc_fuse<<<10,256,0,stream>>>(Pg, fbias[2], fg[2], fbt[2], nullptr, (float*)d_out, 10, 64, 4, 0);
}

// Round 8
// 823.328 us; speedup vs baseline: 9.1449x; 1.0362x over previous
//
#include <hip/hip_runtime.h>
#include <stdint.h>

typedef unsigned short u16;
typedef unsigned int   u32;
typedef __attribute__((ext_vector_type(8))) short bf16x8;
typedef __attribute__((ext_vector_type(4))) float f32x4;

__device__ __forceinline__ float b2f(u16 u){ u32 i = ((u32)u) << 16; float f; __builtin_memcpy(&f,&i,4); return f; }
__device__ __forceinline__ u16 f2b(float f){ u32 i; __builtin_memcpy(&i,&f,4); i += 0x7FFFu + ((i>>16)&1u); return (u16)(i>>16); }

// ---------- weight prep: MFMA B-fragment layout ----------
__global__ void k_prep_wfrag_conv(const float* __restrict__ w, u16* __restrict__ wf,
                                  int Cout, int Cin, int KT){
  int NCT = Cout >> 4;
  int total = KT*NCT*512;
  int Kmax = 9*Cin;
  for(int i = blockIdx.x*256 + threadIdx.x; i < total; i += gridDim.x*256){
    int i8 = i & 7; int lane = (i>>3)&63; int t = i>>9;
    int ct = t % NCT; int kt = t / NCT;
    int k = kt*32 + ((lane>>4)<<3) + i8;
    int co = (ct<<4) + (lane&15);
    u16 v = 0;
    if(k < Kmax){
      int tap = k / Cin; int ci = k - tap*Cin;
      v = (w[(size_t)(co*Cin+ci)*9 + tap] >= 0.f) ? (u16)0x3F80 : (u16)0xBF80;
    }
    wf[i] = v;
  }
}
__global__ void k_prep_wfrag_fc(const float* __restrict__ w, u16* __restrict__ wf,
                                int Nf, int K, int NCTp, int permute){
  int total = (K>>5)*NCTp*512;
  for(int i = blockIdx.x*256 + threadIdx.x; i < total; i += gridDim.x*256){
    int i8 = i & 7; int lane = (i>>3)&63; int t = i>>9;
    int ct = t % NCTp; int kt = t / NCTp;
    int k = kt*32 + ((lane>>4)<<3) + i8;
    int n = (ct<<4) + (lane&15);
    u16 v = 0;
    if(n < Nf){
      int kr = permute ? ((k & 511)*16 + (k >> 9)) : k;
      v = (w[(size_t)n*K + kr] >= 0.f) ? (u16)0x3F80 : (u16)0xBF80;
    }
    wf[i] = v;
  }
}

// x (256,3,32,32) f32 NCHW -> (256,34,34,3) bf16 NHWC edge-padded
__global__ void k_pad_input(const float* __restrict__ x, u16* __restrict__ p){
  int total = 256*34*34*3;
  for(int i = blockIdx.x*256 + threadIdx.x; i < total; i += gridDim.x*256){
    int c = i % 3; int t = i / 3; int wp = t % 34; t /= 34; int hp = t % 34; int n = t / 34;
    int h = hp-1; h = h<0?0:(h>31?31:h);
    int w = wp-1; w = w<0?0:(w>31?31:w);
    p[i] = f2b(x[((size_t)(n*3+c)*32 + h)*32 + w]);
  }
}

// conv1 im2col: padded -> AI[262144][32], k=tap*3+ci, k>=27 zero
__global__ void k_im2col(const u16* __restrict__ xp, u16* __restrict__ AI){
  int m = blockIdx.x*256 + threadIdx.x;
  int w = m & 31; int h = (m>>5)&31; int n = m>>10;
  u16 buf[32];
  #pragma unroll
  for(int j=27;j<32;j++) buf[j]=0;
  #pragma unroll
  for(int tap=0;tap<9;tap++){
    int dh=tap/3, dw=tap-dh*3;
    const u16* s = xp + ((size_t)(n*34 + h+dh)*34 + (w+dw))*3;
    buf[tap*3+0]=s[0]; buf[tap*3+1]=s[1]; buf[tap*3+2]=s[2];
  }
  uint4* d = (uint4*)(AI + (size_t)m*32);
  const uint4* b4 = (const uint4*)buf;
  d[0]=b4[0]; d[1]=b4[1]; d[2]=b4[2]; d[3]=b4[3];
}

// ---------- conv: implicit GEMM MFMA, fused pool+stats (no atomics) ----------
template<int MF,int NF,int CS,int W,int POOL,int STATS>
__global__ __launch_bounds__(256) void k_conv_t(
    const u16* __restrict__ xp, const u16* __restrict__ wf, const float* __restrict__ bias,
    float* __restrict__ y, float* __restrict__ SP,
    int Cin, int NCT, int coutOff, int yOff, int yC)
{
  extern __shared__ u16 lds[];
  __shared__ float sbuf[STATS ? 4*NF*16 : 4];
  constexpr int BM = 2*MF*16;
  constexpr int R  = BM / W;
  constexpr int Wp = W + 2;
  constexpr int S  = CS + 8;
  constexpr int c32cnt = CS >> 5;
  constexpr int c32log = (CS==256)?3:((CS==128)?2:1);
  constexpr int csLog  = (CS==256)?8:((CS==128)?7:6);
  constexpr int wLog   = (W==32)?5:((W==16)?4:3);
  constexpr int hblocks = W / R;
  constexpr int NKt = 9*c32cnt;
  constexpr int BN = 2*NF*16;

  const int tid = threadIdx.x, lane = tid&63, wid = tid>>6;
  const int wm = wid&1, wn = wid>>1;
  const int n  = blockIdx.x / hblocks;
  const int h0 = (blockIdx.x % hblocks) * R;
  const int cb = coutOff + blockIdx.y*BN;
  const int KTall = Cin >> 5;
  const int halves = Cin / CS;
  const int ctb = (cb>>4) + wn*NF;

  int offA[MF];
  #pragma unroll
  for(int fm=0; fm<MF; fm++){
    int p = (wm*MF+fm)*16 + (lane & 15);
    int rl = p >> wLog; int w_ = p & (W-1);
    offA[fm] = (rl*Wp + w_)*S + ((lane>>4)<<3);
  }

  f32x4 acc[MF][NF];
  #pragma unroll
  for(int i=0;i<MF;i++)
    #pragma unroll
    for(int j=0;j<NF;j++) acc[i][j] = (f32x4){0.f,0.f,0.f,0.f};

  constexpr int total8 = ((R+2)*Wp*CS) >> 3;

  for(int hv=0; hv<halves; hv++){
    __syncthreads();
    {
      const u16* gx = xp + ((size_t)(n*(W+2) + h0))*(size_t)(Wp*Cin) + (size_t)hv*CS;
      for(int i8=tid; i8<total8; i8+=256){
        int e = i8 << 3; int pix = e >> csLog; int ci = e & (CS-1);
        *(uint4*)(lds + pix*S + ci) = *(const uint4*)(gx + (size_t)pix*Cin + ci);
      }
    }
    __syncthreads();
    const int ktb = (hv*CS) >> 5;

    auto loadf = [&](int i, bf16x8 (&AF)[MF], bf16x8 (&BF)[NF]){
      int tap = i >> c32log; int c32 = i & (c32cnt-1);
      int dh = (tap*11) >> 5; int dw = tap - dh*3;
      int kt = tap*KTall + ktb + c32;
      const u16* bp = wf + (((size_t)kt*NCT + ctb)*64 + lane)*8;
      #pragma unroll
      for(int fn=0;fn<NF;fn++) BF[fn] = *(const bf16x8*)(bp + fn*512);
      const int toff = (dh*Wp + dw)*S + (c32<<5);
      #pragma unroll
      for(int fm=0;fm<MF;fm++) AF[fm] = *(const bf16x8*)(lds + offA[fm] + toff);
    };
    auto domf = [&](bf16x8 (&AF)[MF], bf16x8 (&BF)[NF]){
      #pragma unroll
      for(int fm=0;fm<MF;fm++)
        #pragma unroll
        for(int fn=0;fn<NF;fn++)
          acc[fm][fn] = __builtin_amdgcn_mfma_f32_16x16x32_bf16(AF[fm],BF[fn],acc[fm][fn],0,0,0);
    };

    bf16x8 Aa[MF], Ba[NF], Ab[MF], Bb2[NF];
    loadf(0, Aa, Ba);
    for(int i=0; i<NKt; i+=2){
      loadf(i+1, Ab, Bb2);
      domf(Aa, Ba);
      int nx = i+2; if(nx > NKt-1) nx = NKt-1;
      loadf(nx, Aa, Ba);
      domf(Ab, Bb2);
    }
  }

  // ---------- epilogue: bias, (pool), write, (stats) ----------
  const int col = lane & 15, g = lane >> 4, rowq = g << 2;
  float sarr[NF], qarr[NF];
  #pragma unroll
  for(int fn=0; fn<NF; fn++){
    const int coutG = cb + (wn*NF+fn)*16 + col;
    const float bs = bias[coutG];
    const int cl = coutG - yOff;
    float vals[MF][4];
    #pragma unroll
    for(int fm=0;fm<MF;fm++)
      #pragma unroll
      for(int ri=0;ri<4;ri++) vals[fm][ri] = acc[fm][fn][ri] + bs;

    float s = 0.f, q = 0.f;
    if constexpr (!POOL){
      #pragma unroll
      for(int fm=0;fm<MF;fm++){
        #pragma unroll
        for(int ri=0;ri<4;ri++){
          int p = (wm*MF+fm)*16 + rowq + ri;
          int rl = p >> wLog; int w_ = p & (W-1);
          y[(((size_t)n*W + h0+rl)*W + w_)*(size_t)yC + cl] = vals[fm][ri];
          if constexpr (STATS){ s += vals[fm][ri]; q += vals[fm][ri]*vals[fm][ri]; }
        }
      }
    } else {
      constexpr int HO = W/2;
      if constexpr (W==32){
        #pragma unroll
        for(int pp=0;pp<2;pp++){
          float pv[4];
          #pragma unroll
          for(int ri=0;ri<4;ri++) pv[ri] = fmaxf(vals[pp][ri], vals[pp+2][ri]);
          float po0 = fmaxf(pv[0],pv[1]), po1 = fmaxf(pv[2],pv[3]);
          int pr = (h0>>1) + wm;
          int wo = pp*8 + (rowq>>1);
          size_t base = (((size_t)n*HO + pr)*HO + wo)*(size_t)yC + cl;
          y[base] = po0; y[base + yC] = po1;
          if constexpr (STATS){ s += po0 + po1; q += po0*po0 + po1*po1; }
        }
      } else if constexpr (W==16){
        #pragma unroll
        for(int pp=0;pp<2;pp++){
          float pv[4];
          #pragma unroll
          for(int ri=0;ri<4;ri++) pv[ri] = fmaxf(vals[2*pp][ri], vals[2*pp+1][ri]);
          float po0 = fmaxf(pv[0],pv[1]), po1 = fmaxf(pv[2],pv[3]);
          int pr = (h0>>1) + wm*2 + pp;
          int wo = (rowq>>1);
          size_t base = (((size_t)n*HO + pr)*HO + wo)*(size_t)yC + cl;
          y[base] = po0; y[base + yC] = po1;
          if constexpr (STATS){ s += po0 + po1; q += po0*po0 + po1*po1; }
        }
      } else { // W==8, MF==2: vertical pair across lane^32
        #pragma unroll
        for(int fm=0;fm<2;fm++){
          float pv[4];
          #pragma unroll
          for(int ri=0;ri<4;ri++){
            float o = __shfl_xor(vals[fm][ri], 32);
            pv[ri] = fmaxf(vals[fm][ri], o);
          }
          if(g < 2){
            float po0 = fmaxf(pv[0],pv[1]), po1 = fmaxf(pv[2],pv[3]);
            int pr = wm*2 + fm;
            int wo = g*2;
            size_t base = (((size_t)n*HO + pr)*HO + wo)*(size_t)yC + cl;
            y[base] = po0; y[base + yC] = po1;
            if constexpr (STATS){ s += po0 + po1; q += po0*po0 + po1*po1; }
          }
        }
      }
    }
    if constexpr (STATS){
      s += __shfl_xor(s, 16); s += __shfl_xor(s, 32);
      q += __shfl_xor(q, 16); q += __shfl_xor(q, 32);
      sarr[fn] = s; qarr[fn] = q;
    }
  }
  if constexpr (STATS){
    if(wm==1 && lane<16){
      #pragma unroll
      for(int fn=0;fn<NF;fn++){
        int lc = (wn*NF+fn)*16 + col;
        sbuf[lc] = sarr[fn]; sbuf[BN+lc] = qarr[fn];
      }
    }
    __syncthreads();
    if(wm==0 && lane<16){
      #pragma unroll
      for(int fn=0;fn<NF;fn++){
        int lc = (wn*NF+fn)*16 + col;
        int cl = cb + (wn*NF+fn)*16 + col - yOff;
        SP[(size_t)blockIdx.x*2*yC + cl]      = sarr[fn] + sbuf[lc];
        SP[(size_t)blockIdx.x*2*yC + yC + cl] = qarr[fn] + sbuf[BN+lc];
      }
    }
  }
}

// ---------- conv1 GEMM over im2col (K=32). MODE 0: stats only. MODE 1: BN+act+padded bf16 out ----------
template<int MODE>
__global__ __launch_bounds__(256) void k_gemm_c1(
    const u16* __restrict__ A, const u16* __restrict__ wf, const float* __restrict__ bias,
    float* __restrict__ SP, const float* __restrict__ AB, u16* __restrict__ outp,
    int K, int NCT, int yC)
{
  __shared__ float sb[128];
  const int tid = threadIdx.x; const int lane = tid & 63; const int wid = tid >> 6;
  const int wm = wid & 1, wn = wid >> 1;
  const int mb = blockIdx.x*64;
  const int coutOff = blockIdx.y*64;
  const int col = lane & 15;
  f32x4 acc[2][2];
  #pragma unroll
  for(int i=0;i<2;i++){ acc[i][0]=(f32x4){0.f,0.f,0.f,0.f}; acc[i][1]=(f32x4){0.f,0.f,0.f,0.f}; }
  const u16* a0p = A + (size_t)(mb + wm*32 + col)*K + ((lane>>4)<<3);
  const u16* a1p = a0p + (size_t)16*K;
  const int ct = (coutOff>>4) + wn*2;
  const int KT = K >> 5;
  for(int kt=0; kt<KT; kt++){
    bf16x8 a0 = *(const bf16x8*)(a0p + (size_t)kt*32);
    bf16x8 a1 = *(const bf16x8*)(a1p + (size_t)kt*32);
    const u16* bp = wf + (((size_t)kt*NCT + ct)*64 + lane)*8;
    bf16x8 b0 = *(const bf16x8*)(bp);
    bf16x8 b1 = *(const bf16x8*)(bp + 512);
    acc[0][0] = __builtin_amdgcn_mfma_f32_16x16x32_bf16(a0,b0,acc[0][0],0,0,0);
    acc[0][1] = __builtin_amdgcn_mfma_f32_16x16x32_bf16(a0,b1,acc[0][1],0,0,0);
    acc[1][0] = __builtin_amdgcn_mfma_f32_16x16x32_bf16(a1,b0,acc[1][0],0,0,0);
    acc[1][1] = __builtin_amdgcn_mfma_f32_16x16x32_bf16(a1,b1,acc[1][1],0,0,0);
  }
  const int rowq = (lane>>4)<<2;
  if constexpr (MODE == 0){
    float sarr[2], qarr[2];
    #pragma unroll
    for(int fn=0; fn<2; fn++){
      int coutG = wn*32 + fn*16 + col + coutOff;
      float bs = bias[coutG];
      float s=0.f, q=0.f;
      #pragma unroll
      for(int fm=0; fm<2; fm++){
        #pragma unroll
        for(int ri=0; ri<4; ri++){
          float v = acc[fm][fn][ri] + bs;
          s += v; q += v*v;
        }
      }
      s += __shfl_xor(s, 16); s += __shfl_xor(s, 32);
      q += __shfl_xor(q, 16); q += __shfl_xor(q, 32);
      sarr[fn]=s; qarr[fn]=q;
    }
    if(wm==1 && lane<16){
      #pragma unroll
      for(int fn=0;fn<2;fn++){ int lc = wn*32+fn*16+col; sb[lc]=sarr[fn]; sb[64+lc]=qarr[fn]; }
    }
    __syncthreads();
    if(wm==0 && lane<16){
      #pragma unroll
      for(int fn=0;fn<2;fn++){
        int lc = wn*32+fn*16+col;
        int cl = coutOff + lc;
        SP[(size_t)blockIdx.x*2*yC + cl]      = sarr[fn] + sb[lc];
        SP[(size_t)blockIdx.x*2*yC + yC + cl] = qarr[fn] + sb[64+lc];
      }
    }
  } else {
    // BN + hardtanh + padded bf16 write with edge replication
    #pragma unroll
    for(int fn=0; fn<2; fn++){
      int c = wn*32 + fn*16 + col + coutOff;
      float bs = bias[c];
      float Ac = AB[c], Bc = AB[128 + c];
      #pragma unroll
      for(int fm=0; fm<2; fm++){
        #pragma unroll
        for(int ri=0; ri<4; ri++){
          int m = mb + wm*32 + fm*16 + rowq + ri;
          int w = m & 31, h = (m>>5)&31, n = m>>10;
          float o = (acc[fm][fn][ri] + bs)*Ac + Bc;
          o = fminf(fmaxf(o, -1.f), 1.f);
          u16 b = f2b(o);
          u16* ob = outp + (size_t)n*34*34*128;
          #define WR1(hp,wp) ob[((size_t)(hp)*34 + (wp))*128 + c] = b
          WR1(h+1, w+1);
          if(h==0)        WR1(0,  w+1);
          if(h==31)       WR1(33, w+1);
          if(w==0)        WR1(h+1, 0);
          if(w==31)       WR1(h+1, 33);
          if(h==0 && w==0)   WR1(0, 0);
          if(h==0 && w==31)  WR1(0, 33);
          if(h==31 && w==0)  WR1(33, 0);
          if(h==31 && w==31) WR1(33, 33);
          #undef WR1
        }
      }
    }
  }
}

// ---------- FC GEMM, split-K, fp32 partials (TRANSPOSED: P[(kz*ncp+c)*M+m]) ----------
__global__ __launch_bounds__(256) void k_gemm_part(
    const u16* __restrict__ A, const u16* __restrict__ wf, float* __restrict__ P,
    int M, int K, int NCT, int ncp, int KTC)
{
  const int tid = threadIdx.x; const int lane = tid & 63; const int wid = tid >> 6;
  const int wm = wid & 1, wn = wid >> 1;
  const int mb = blockIdx.x*64, nb = blockIdx.y*64, kz = blockIdx.z;
  const int col = lane & 15;
  f32x4 acc[2][2];
  #pragma unroll
  for(int i=0;i<2;i++){ acc[i][0]=(f32x4){0.f,0.f,0.f,0.f}; acc[i][1]=(f32x4){0.f,0.f,0.f,0.f}; }
  const u16* a0p = A + (size_t)(mb + wm*32 + col)*K + ((lane>>4)<<3);
  const u16* a1p = a0p + (size_t)16*K;
  const int kt0 = kz*KTC;
  for(int t=0; t<KTC; t++){
    int kt = kt0 + t;
    bf16x8 a0 = *(const bf16x8*)(a0p + (size_t)kt*32);
    bf16x8 a1 = *(const bf16x8*)(a1p + (size_t)kt*32);
    const u16* bp = wf + (((size_t)kt*NCT + (nb>>4) + wn*2)*64 + lane)*8;
    bf16x8 b0 = *(const bf16x8*)(bp);
    bf16x8 b1 = *(const bf16x8*)(bp + 512);
    acc[0][0] = __builtin_amdgcn_mfma_f32_16x16x32_bf16(a0,b0,acc[0][0],0,0,0);
    acc[0][1] = __builtin_amdgcn_mfma_f32_16x16x32_bf16(a0,b1,acc[0][1],0,0,0);
    acc[1][0] = __builtin_amdgcn_mfma_f32_16x16x32_bf16(a1,b0,acc[1][0],0,0,0);
    acc[1][1] = __builtin_amdgcn_mfma_f32_16x16x32_bf16(a1,b1,acc[1][1],0,0,0);
  }
  const int rowq = (lane>>4)<<2;
  #pragma unroll
  for(int fm=0; fm<2; fm++){
    #pragma unroll
    for(int fn=0; fn<2; fn++){
      int mbase = mb + wm*32 + fm*16 + rowq;
      int c = nb + wn*32 + fn*16 + col;
      *(f32x4*)(P + ((size_t)kz*ncp + c)*M + mbase) = acc[fm][fn];
    }
  }
}

// ---------- fused FC finish: sum partials + bias -> batch-BN -> act -> write ----------
__global__ __launch_bounds__(256) void k_fc_fuse(
    const float* __restrict__ P, const float* __restrict__ bias,
    const float* __restrict__ g, const float* __restrict__ bt,
    u16* __restrict__ outb, float* __restrict__ outf,
    int Nf, int ncp, int CH, int clampF)
{
  __shared__ float sb[10];
  const int nf = blockIdx.x; const int m = threadIdx.x;   // M == 256
  float v = bias[nf];
  for(int z=0; z<CH; z++) v += P[((size_t)z*ncp + nf)*256 + m];
  float s = v, q = v*v;
  #pragma unroll
  for(int d=1; d<64; d<<=1){ s += __shfl_xor(s,d); q += __shfl_xor(q,d); }
  if((m&63)==0){ sb[m>>6]=s; sb[4+(m>>6)]=q; }
  __syncthreads();
  if(m==0){
    float st=sb[0]+sb[1]+sb[2]+sb[3], qt=sb[4]+sb[5]+sb[6]+sb[7];
    float mean=st*(1.f/256.f); float var=qt*(1.f/256.f)-mean*mean;
    float A=g[nf]*rsqrtf(var+1e-5f);
    sb[8]=A; sb[9]=bt[nf]-mean*A;
  }
  __syncthreads();
  float o = v*sb[8]+sb[9];
  if(clampF) o = fminf(fmaxf(o,-1.f),1.f);
  if(outb) outb[(size_t)m*Nf+nf] = f2b(o);
  else     outf[(size_t)m*Nf+nf] = o;
}

// reduce partial rows -> AB[cbase+c]=A, AB[Cfull+cbase+c]=B. One block per channel.
__global__ void k_bn_prep2(const float* __restrict__ part, const float* __restrict__ g,
                           const float* __restrict__ bt, float* __restrict__ AB,
                           int C, int rows, float invCnt, int cbase, int Cfull){
  __shared__ float ls[512];
  int c = blockIdx.x; int tid = threadIdx.x;
  float s=0.f, q=0.f;
  for(int r=tid; r<rows; r+=256){ s += part[(size_t)r*2*C + c]; q += part[(size_t)r*2*C + C + c]; }
  ls[tid]=s; ls[256+tid]=q; __syncthreads();
  for(int st=128; st>0; st>>=1){
    if(tid<st){ ls[tid]+=ls[tid+st]; ls[256+tid]+=ls[256+tid+st]; }
    __syncthreads();
  }
  if(tid==0){
    float m = ls[0]*invCnt; float v = ls[256]*invCnt - m*m;
    float A = g[c]*rsqrtf(v + 1e-5f);
    AB[cbase+c] = A; AB[Cfull+cbase+c] = bt[c] - m*A;
  }
}

// normalize(fp32 in) + hardtanh + bf16 write (padded-with-edge-replication or flat)
__global__ void k_bn_act_f32(const float* __restrict__ in, const float* __restrict__ Aa,
                             const float* __restrict__ Bb, u16* __restrict__ out,
                             int Cbuf, int rows, int HO, int WO, int Cfull, int cbase,
                             int padMode, int clampF){
  int cpg = Cbuf >> 3;
  int total = rows * cpg;
  for(int i = blockIdx.x*256 + threadIdx.x; i < total; i += gridDim.x*256){
    int c8 = i % cpg; int row = i / cpg; int c0 = c8*8;
    float4 v0 = *(const float4*)(in + (size_t)i*8);
    float4 v1 = *(const float4*)(in + (size_t)i*8 + 4);
    float4 A0 = *(const float4*)(Aa + c0);
    float4 A1 = *(const float4*)(Aa + c0 + 4);
    float4 B0 = *(const float4*)(Bb + c0);
    float4 B1 = *(const float4*)(Bb + c0 + 4);
    float f[8];
    f[0]=v0.x*A0.x+B0.x; f[1]=v0.y*A0.y+B0.y; f[2]=v0.z*A0.z+B0.z; f[3]=v0.w*A0.w+B0.w;
    f[4]=v1.x*A1.x+B1.x; f[5]=v1.y*A1.y+B1.y; f[6]=v1.z*A1.z+B1.z; f[7]=v1.w*A1.w+B1.w;
    if(clampF){
      #pragma unroll
      for(int j=0;j<8;j++) f[j] = fminf(fmaxf(f[j], -1.f), 1.f);
    }
    uint4 o;
    o.x = (u32)f2b(f[0]) | ((u32)f2b(f[1])<<16);
    o.y = (u32)f2b(f[2]) | ((u32)f2b(f[3])<<16);
    o.z = (u32)f2b(f[4]) | ((u32)f2b(f[5])<<16);
    o.w = (u32)f2b(f[6]) | ((u32)f2b(f[7])<<16);
    if(!padMode){
      *(uint4*)(out + (size_t)row*Cbuf + c0) = o;
    } else {
      int w = row % WO; int t = row / WO; int h = t % HO; int n = t / HO;
      int Wp2 = WO + 2;
      size_t base = (size_t)n*(HO+2)*Wp2;
      #define WRP(hp,wp) *(uint4*)(out + ((base + (size_t)(hp)*Wp2 + (wp))*(size_t)Cfull) + cbase + c0) = o
      WRP(h+1, w+1);
      if(h==0)            WRP(0,    w+1);
      if(h==HO-1)         WRP(HO+1, w+1);
      if(w==0)            WRP(h+1,  0);
      if(w==WO-1)         WRP(h+1,  WO+1);
      if(h==0    && w==0)    WRP(0,    0);
      if(h==0    && w==WO-1) WRP(0,    WO+1);
      if(h==HO-1 && w==0)    WRP(HO+1, 0);
      if(h==HO-1 && w==WO-1) WRP(HO+1, WO+1);
      #undef WRP
    }
  }
}

// ================= host =================
extern "C" void kernel_launch(void* const* d_in, const int* in_sizes, int n_in,
                              void* d_out, int out_size, void* d_ws, size_t ws_size,
                              hipStream_t stream) {
  (void)in_sizes; (void)n_in; (void)out_size; (void)ws_size;
  const float* x = (const float*)d_in[0];
  const float *cw[6], *cb[6], *cgam[6], *cbt[6];
  for(int i=0;i<6;i++){
    cw[i]  =(const float*)d_in[1+4*i];
    cb[i]  =(const float*)d_in[2+4*i];
    cgam[i]=(const float*)d_in[3+4*i];
    cbt[i] =(const float*)d_in[4+4*i];
  }
  const float *fw[3], *fbias[3], *fg[3], *fbt[3];
  for(int i=0;i<3;i++){
    fw[i]   =(const float*)d_in[25+4*i];
    fbias[i]=(const float*)d_in[26+4*i];
    fg[i]   =(const float*)d_in[27+4*i];
    fbt[i]  =(const float*)d_in[28+4*i];
  }

  char* ws = (char*)d_ws;
  size_t off = 0;
  auto alloc = [&](size_t bytes){ size_t o = off; off = (off + bytes + 255) & ~(size_t)255; return o; };
  const size_t oX  = alloc((size_t)256*34*34*3*2);
  const size_t oP  = alloc((size_t)256*34*34*128*2);      // padded acts A; later FC wfrags
  const size_t oP2 = alloc((size_t)256*18*18*128*2);      // padded acts B
  const size_t oYf = alloc((size_t)67108864);             // fp32 pre-BN / pooled out; later FC bufs
  const size_t oQf = alloc((size_t)16777216);             // AI im2col; later F0
  const int CinA[6]  = {3,128,128,256,256,512};
  const int CoutA[6] = {128,128,256,256,512,512};
  const int KTA[6]   = {1,36,36,72,72,144};
  size_t oWc[6];
  for(int l=0;l<6;l++) oWc[l] = alloc((size_t)KTA[l]*(CoutA[l]>>4)*512*2);
  const size_t oSP = alloc((size_t)4096*256*4);           // stats partial rows (4MB)
  const size_t oAB = alloc((size_t)2*1536*4);

  u16*   X    = (u16*)(ws + oX);
  u16*   Pb   = (u16*)(ws + oP);
  u16*   P2   = (u16*)(ws + oP2);
  float* Yf   = (float*)(ws + oYf);
  u16*   AI   = (u16*)(ws + oQf);
  u16*   F0   = (u16*)(ws + oQf);       // bf16 256x8192 (4.2MB), written after AI is dead
  float* SP   = (float*)(ws + oSP);
  float* AB   = (float*)(ws + oAB);
  float* Pg   = (float*)(ws + oYf + (size_t)32*1024*1024); // split-K partials (25.2MB max)
  u16*   FAa  = (u16*)(ws + oYf + (size_t)58*1024*1024);
  u16*   FBa  = (u16*)(ws + oYf + (size_t)60*1024*1024);
  u16* Wf1 = (u16*)(ws + oP);
  u16* Wf2 = (u16*)(ws + oP + (size_t)26*1024*1024);
  u16* Wf3 = (u16*)(ws + oP + (size_t)31*1024*1024);

  for(int l=0;l<6;l++)
    k_prep_wfrag_conv<<<1024,256,0,stream>>>(cw[l], (u16*)(ws+oWc[l]), CoutA[l], CinA[l], KTA[l]);
  k_pad_input<<<2048,256,0,stream>>>(x, X);
  k_im2col<<<1024,256,0,stream>>>(X, AI);

  // ---- conv1: pass1 stats-only, bn_prep, pass2 fused BN+act+padded write ----
  k_gemm_c1<0><<<dim3(4096,2),256,0,stream>>>(AI, (u16*)(ws+oWc[0]), cb[0], SP, nullptr, nullptr, 32, 8, 128);
  k_bn_prep2<<<128,256,0,stream>>>(SP, cgam[0], cbt[0], AB, 128, 4096, 1.0f/262144.0f, 0, 128);
  k_gemm_c1<1><<<dim3(4096,2),256,0,stream>>>(AI, (u16*)(ws+oWc[0]), cb[0], nullptr, AB, Pb, 32, 8, 128);

  // ---- conv2: fused pool+stats, Pb -> Yf(pooled fp32) -> P2 ----
  k_conv_t<4,2,64,32,1,1><<<dim3(2048,2),256,29376,stream>>>(Pb, (u16*)(ws+oWc[1]), cb[1], Yf, SP, 128, 8, 0, 0, 128);
  k_bn_prep2<<<128,256,0,stream>>>(SP, cgam[1], cbt[1], AB, 128, 2048, 1.0f/65536.0f, 0, 128);
  k_bn_act_f32<<<2048,256,0,stream>>>(Yf, AB, AB+128, P2, 128, 65536, 16, 16, 128, 0, 1, 1);
  // ---- conv3: fused stats, P2 -> Yf -> Pb ----
  k_conv_t<4,2,64,16,0,1><<<dim3(512,4),256,25920,stream>>>(P2, (u16*)(ws+oWc[2]), cb[2], Yf, SP, 128, 16, 0, 0, 256);
  k_bn_prep2<<<256,256,0,stream>>>(SP, cgam[2], cbt[2], AB, 256, 512, 1.0f/65536.0f, 0, 256);
  k_bn_act_f32<<<2048,256,0,stream>>>(Yf, AB, AB+256, Pb, 256, 65536, 16, 16, 256, 0, 1, 1);
  // ---- conv4: fused pool+stats, Pb -> Yf(pooled) -> P2 ----
  k_conv_t<4,2,64,16,1,1><<<dim3(512,4),256,25920,stream>>>(Pb, (u16*)(ws+oWc[3]), cb[3], Yf, SP, 256, 16, 0, 0, 256);
  k_bn_prep2<<<256,256,0,stream>>>(SP, cgam[3], cbt[3], AB, 256, 512, 1.0f/16384.0f, 0, 256);
  k_bn_act_f32<<<2048,256,0,stream>>>(Yf, AB, AB+256, P2, 256, 16384, 8, 8, 256, 0, 1, 1);
  // ---- conv5: fused stats, P2 -> Yf -> Pb ----
  k_conv_t<2,2,64,8,0,1><<<dim3(256,8),256,14400,stream>>>(P2, (u16*)(ws+oWc[4]), cb[4], Yf, SP, 256, 32, 0, 0, 512);
  k_bn_prep2<<<512,256,0,stream>>>(SP, cgam[4], cbt[4], AB, 512, 256, 1.0f/16384.0f, 0, 512);
  k_bn_act_f32<<<2048,256,0,stream>>>(Yf, AB, AB+512, Pb, 512, 16384, 8, 8, 512, 0, 1, 1);
  // ---- conv6: fused pool+stats, Pb -> Yf(pooled) -> F0 ----
  k_conv_t<2,2,64,8,1,1><<<dim3(256,8),256,14400,stream>>>(Pb, (u16*)(ws+oWc[5]), cb[5], Yf, SP, 512, 32, 0, 0, 512);
  k_bn_prep2<<<512,256,0,stream>>>(SP, cgam[5], cbt[5], AB, 512, 256, 1.0f/4096.0f, 0, 512);
  k_bn_act_f32<<<512,256,0,stream>>>(Yf, AB, AB+512, F0, 512, 4096, 4, 4, 512, 0, 0, 1);

  // ---- FC weight fragments (oP is dead now) ----
  k_prep_wfrag_fc<<<2048,256,0,stream>>>(fw[0], Wf1, 1536, 8192, 96, 1);
  k_prep_wfrag_fc<<<1024,256,0,stream>>>(fw[1], Wf2, 1536, 1536, 96, 0);
  k_prep_wfrag_fc<<<64,256,0,stream>>>  (fw[2], Wf3, 10,   1536, 4,  0);

  // FC1
  k_gemm_part<<<dim3(4,24,16),256,0,stream>>>(F0, Wf1, Pg, 256, 8192, 96, 1536, 16);
  k_fc_fuse<<<1536,256,0,stream>>>(Pg, fbias[0], fg[0], fbt[0], FAa, nullptr, 1536, 1536, 16, 1);
  // FC2
  k_gemm_part<<<dim3(4,24,8),256,0,stream>>>(FAa, Wf2, Pg, 256, 1536, 96, 1536, 6);
  k_fc_fuse<<<1536,256,0,stream>>>(Pg, fbias[1], fg[1], fbt[1], FBa, nullptr, 1536, 1536, 8, 1);
  // FC3 (N padded to 64) -> BN (no clamp) -> f32 out
  k_gemm_part<<<dim3(4,1,4),256,0,stream>>>(FBa, Wf3, Pg, 256, 1536, 4, 64, 12);
  k_fc_fuse<<<10,256,0,stream>>>(Pg, fbias[2], fg[2], fbt[2], nullptr, (float*)d_out, 10, 64, 4, 0);
}